// Round 1
// baseline (1191.321 us; speedup 1.0000x reference)
//
#include <hip/hip_runtime.h>

// LimbOrientationPredictor fused kernel (MI355X / gfx950)
// M = 65536*14 = 917504 rows. Per row: build lf[256] features, h1(256->128)+LN+leaky,
// h2(128->128)+leaky, h3(128->3), out = unit(cur + delta).
// 256 persistent blocks x 512 threads (8 waves). Weights staged bf16 in LDS once/block.

#define NTILES 14336   // 917504 / 64
#define NTHR   512

typedef __bf16 bf16x8 __attribute__((ext_vector_type(8)));
typedef float  f32x4  __attribute__((ext_vector_type(4)));

// PARENT-5 / CHILD-5 packed as 4-bit nibbles, l = 0..13
#define PARENT_PK 0x10106097863120ull
#define CHILD_PK  0x677671b9a85342ull

struct Smem {
  __bf16 W1[128][264];   // h1_w, rows padded 256->264 (2-way bank alias only)
  __bf16 W2[128][136];   // h2_w, 128->136
  __bf16 lf[64][264];    // feature tile [l2(64) co(32) pf(64) cf(64) vf(32)]
  __bf16 h [64][136];    // post-LN/leaky h1 output
  float4 w3t[128];       // h3_w transposed: w3t[c] = {w3[0][c], w3[1][c], w3[2][c], 0}
  float  h1b[128], hg[128], hbe[128], h2b[128];
  float  h3b[4];
  float  cur[64][4];     // unit bone vectors per row
  float4 part[256];      // [row][wave_n] partials (LN sums, then delta partials)
};

__device__ __forceinline__ float red16(float v) {  // sum across lanes sharing lane>>4
  v += __shfl_xor(v, 1, 64);
  v += __shfl_xor(v, 2, 64);
  v += __shfl_xor(v, 4, 64);
  v += __shfl_xor(v, 8, 64);
  return v;
}

__global__ __launch_bounds__(NTHR) void limb_kernel(
    const float* __restrict__ jf,  const float* __restrict__ p3g,
    const float* __restrict__ az,  const float* __restrict__ el,
    const float* __restrict__ p2d,
    const float* __restrict__ cow, const float* __restrict__ cob,
    const float* __restrict__ cog, const float* __restrict__ cobe,
    const float* __restrict__ l2w, const float* __restrict__ l2b,
    const float* __restrict__ l2g, const float* __restrict__ l2be,
    const float* __restrict__ vw,  const float* __restrict__ vb,
    const float* __restrict__ w1,  const float* __restrict__ h1bg,
    const float* __restrict__ hgg, const float* __restrict__ hbeg,
    const float* __restrict__ w2,  const float* __restrict__ h2bg,
    const float* __restrict__ w3,  const float* __restrict__ h3bg,
    float* __restrict__ out)
{
  __shared__ Smem sm;
  const int tid  = threadIdx.x;
  const int wave = tid >> 6;
  const int lane = tid & 63;

  // ---- one-time weight staging (fp32 global -> bf16 LDS) ----
  for (int i = tid; i < 128 * 256; i += NTHR) sm.W1[i >> 8][i & 255] = (__bf16)w1[i];
  for (int i = tid; i < 128 * 128; i += NTHR) sm.W2[i >> 7][i & 127] = (__bf16)w2[i];
  if (tid < 384) { int o = tid >> 7, c = tid & 127; ((float*)&sm.w3t[c])[o] = w3[tid]; }
  if (tid < 128) {
    sm.h1b[tid] = h1bg[tid]; sm.hg[tid] = hgg[tid];
    sm.hbe[tid] = hbeg[tid]; sm.h2b[tid] = h2bg[tid];
  }
  if (tid < 4) sm.h3b[tid] = (tid < 3) ? h3bg[tid] : 0.f;

  // ---- per-lane small-net params (constant across all rows) ----
  const float lw0 = l2w[lane * 4 + 0], lw1 = l2w[lane * 4 + 1];
  const float lw2 = l2w[lane * 4 + 2], lw3 = l2w[lane * 4 + 3];
  const float lbv = l2b[lane], lgv = l2g[lane], lbev = l2be[lane];
  float cw0 = 0.f, cw1 = 0.f, cw2 = 0.f, cbv = 0.f, cgv = 0.f, cbev = 0.f;
  float vwv[7] = {0.f, 0.f, 0.f, 0.f, 0.f, 0.f, 0.f};
  float vbv = 0.f;
  if (lane < 32) {
    cw0 = cow[lane * 3 + 0]; cw1 = cow[lane * 3 + 1]; cw2 = cow[lane * 3 + 2];
    cbv = cob[lane]; cgv = cog[lane]; cbev = cobe[lane];
  } else {
    const int o = lane - 32;
    #pragma unroll
    for (int k = 0; k < 7; ++k) vwv[k] = vw[o * 7 + k];
    vbv = vb[o];
  }

  const int wm = wave >> 2, wn = wave & 3;  // 2 (M) x 4 (N) wave grid
  const int lrow = lane & 15, lk8 = lane >> 4;
  const int am0 = wm * 32 + lrow, am1 = am0 + 16;   // A rows
  const int bn0 = wn * 32 + lrow, bn1 = bn0 + 16;   // B cols

  __syncthreads();

  for (int tile = blockIdx.x; tile < NTILES; tile += gridDim.x) {
    const int rg0 = tile * 64;

    // =========== Phase F: build lf tile (each wave: 8 rows) ===========
    for (int rr = 0; rr < 8; ++rr) {
      const int row = wave * 8 + rr;
      const unsigned rg = (unsigned)(rg0 + row);
      const unsigned b = rg / 14u;
      const int l = (int)(rg - b * 14u);
      const int p = 5 + (int)((PARENT_PK >> (4 * l)) & 15ull);
      const int c = 5 + (int)((CHILD_PK  >> (4 * l)) & 15ull);

      const float* p3 = p3g + (size_t)b * 51;
      const float dx = p3[c * 3 + 0] - p3[p * 3 + 0];
      const float dy = p3[c * 3 + 1] - p3[p * 3 + 1];
      const float dz = p3[c * 3 + 2] - p3[p * 3 + 2];
      const float cn = sqrtf(dx * dx + dy * dy + dz * dz);
      const float ci = 1.f / fmaxf(cn, 1e-6f);
      const float cx = dx * ci, cy = dy * ci, cz = dz * ci;
      if (lane == 0) { sm.cur[row][0] = cx; sm.cur[row][1] = cy; sm.cur[row][2] = cz; }

      const float* q2 = p2d + (size_t)b * 34;
      const float vx = q2[c * 2 + 0] - q2[p * 2 + 0];
      const float vy = q2[c * 2 + 1] - q2[p * 2 + 1];
      const float L  = sqrtf(vx * vx + vy * vy);
      const float il = 1.f / (L + 1e-6f);
      const float f0 = vx * il, f1 = vy * il, f3 = L * (1.f / (0.15f + 1e-6f));

      // l2: all 64 lanes, o = lane; LN over 64
      {
        const float a = lw0 * f0 + lw1 * f1 + lw2 * L + lw3 * f3 + lbv;
        float s = a, q = a * a;
        #pragma unroll
        for (int m = 1; m < 64; m <<= 1) { s += __shfl_xor(s, m, 64); q += __shfl_xor(q, m, 64); }
        const float mean = s * (1.f / 64.f);
        const float var  = q * (1.f / 64.f) - mean * mean;
        const float y = (a - mean) * rsqrtf(var + 1e-5f) * lgv + lbev;
        sm.lf[row][lane] = (__bf16)fmaxf(y, 0.f);
      }

      if (lane < 32) {  // co: LN over 32
        const float a = cw0 * cx + cw1 * cy + cw2 * cz + cbv;
        float s = a, q = a * a;
        #pragma unroll
        for (int m = 1; m < 32; m <<= 1) { s += __shfl_xor(s, m, 64); q += __shfl_xor(q, m, 64); }
        const float mean = s * (1.f / 32.f);
        const float var  = q * (1.f / 32.f) - mean * mean;
        const float y = (a - mean) * rsqrtf(var + 1e-5f) * cgv + cbev;
        sm.lf[row][64 + lane] = (__bf16)fmaxf(y, 0.f);
      } else {          // vf: relu only
        const float azr = az[b] * 0.017453292519943295f;
        const float elr = el[b] * 0.017453292519943295f;
        const float sa = sinf(azr), ca = cosf(azr), se = sinf(elr), ce = cosf(elr);
        const float a = vwv[0] * (sa * ce) + vwv[1] * se + vwv[2] * (ca * ce) +
                        vwv[3] * sa + vwv[4] * ca + vwv[5] * se + vwv[6] * ce + vbv;
        sm.lf[row][224 + (lane - 32)] = (__bf16)fmaxf(a, 0.f);
      }

      // pf / cf copies (coalesced 256B per load)
      const float* jp = jf + ((size_t)b * 17 + (size_t)p) * 64;
      const float* jc = jf + ((size_t)b * 17 + (size_t)c) * 64;
      sm.lf[row][96 + lane]  = (__bf16)jp[lane];
      sm.lf[row][160 + lane] = (__bf16)jc[lane];
    }
    __syncthreads();

    // =========== Phase G1: h1 = lf @ W1^T (64x256x128), LN + leaky ===========
    f32x4 a00 = {0.f, 0.f, 0.f, 0.f}, a01 = a00, a10 = a00, a11 = a00;
    #pragma unroll
    for (int kk = 0; kk < 8; ++kk) {
      const int ko = kk * 32 + lk8 * 8;
      const bf16x8 fa0 = *(const bf16x8*)&sm.lf[am0][ko];
      const bf16x8 fa1 = *(const bf16x8*)&sm.lf[am1][ko];
      const bf16x8 fb0 = *(const bf16x8*)&sm.W1[bn0][ko];
      const bf16x8 fb1 = *(const bf16x8*)&sm.W1[bn1][ko];
      a00 = __builtin_amdgcn_mfma_f32_16x16x32_bf16(fa0, fb0, a00, 0, 0, 0);
      a01 = __builtin_amdgcn_mfma_f32_16x16x32_bf16(fa0, fb1, a01, 0, 0, 0);
      a10 = __builtin_amdgcn_mfma_f32_16x16x32_bf16(fa1, fb0, a10, 0, 0, 0);
      a11 = __builtin_amdgcn_mfma_f32_16x16x32_bf16(fa1, fb1, a11, 0, 0, 0);
    }
    // bias + LN partial sums (wave covers 32 cols per row)
    const float hb0 = sm.h1b[bn0], hb1 = sm.h1b[bn1];
    float v00[4], v01[4], v10[4], v11[4];
    #pragma unroll
    for (int j = 0; j < 4; ++j) {
      v00[j] = a00[j] + hb0; v01[j] = a01[j] + hb1;
      v10[j] = a10[j] + hb0; v11[j] = a11[j] + hb1;
    }
    #pragma unroll
    for (int mi = 0; mi < 2; ++mi) {
      #pragma unroll
      for (int j = 0; j < 4; ++j) {
        const float x0 = mi ? v10[j] : v00[j];
        const float x1 = mi ? v11[j] : v01[j];
        const float ss = red16(x0 + x1);
        const float qq = red16(x0 * x0 + x1 * x1);
        if (lrow == 0) {
          const int r = wm * 32 + mi * 16 + lk8 * 4 + j;
          sm.part[r * 4 + wn] = make_float4(ss, qq, 0.f, 0.f);
        }
      }
    }
    __syncthreads();
    {
      const float g0 = sm.hg[bn0], g1 = sm.hg[bn1];
      const float e0 = sm.hbe[bn0], e1 = sm.hbe[bn1];
      #pragma unroll
      for (int mi = 0; mi < 2; ++mi) {
        #pragma unroll
        for (int j = 0; j < 4; ++j) {
          const int r = wm * 32 + mi * 16 + lk8 * 4 + j;
          const float4 pA = sm.part[r * 4 + 0], pB = sm.part[r * 4 + 1];
          const float4 pC = sm.part[r * 4 + 2], pD = sm.part[r * 4 + 3];
          const float mean = (pA.x + pB.x + pC.x + pD.x) * (1.f / 128.f);
          const float var  = (pA.y + pB.y + pC.y + pD.y) * (1.f / 128.f) - mean * mean;
          const float rs = rsqrtf(var + 1e-5f);
          const float x0 = mi ? v10[j] : v00[j];
          const float x1 = mi ? v11[j] : v01[j];
          float y0 = (x0 - mean) * rs * g0 + e0; y0 = (y0 > 0.f) ? y0 : 0.2f * y0;
          float y1 = (x1 - mean) * rs * g1 + e1; y1 = (y1 > 0.f) ? y1 : 0.2f * y1;
          sm.h[r][bn0] = (__bf16)y0;
          sm.h[r][bn1] = (__bf16)y1;
        }
      }
    }
    __syncthreads();

    // =========== Phase G2: h2 = h @ W2^T (64x128x128), leaky + fused h3 dot ===========
    f32x4 d00 = {0.f, 0.f, 0.f, 0.f}, d01 = d00, d10 = d00, d11 = d00;
    #pragma unroll
    for (int kk = 0; kk < 4; ++kk) {
      const int ko = kk * 32 + lk8 * 8;
      const bf16x8 fa0 = *(const bf16x8*)&sm.h[am0][ko];
      const bf16x8 fa1 = *(const bf16x8*)&sm.h[am1][ko];
      const bf16x8 fb0 = *(const bf16x8*)&sm.W2[bn0][ko];
      const bf16x8 fb1 = *(const bf16x8*)&sm.W2[bn1][ko];
      d00 = __builtin_amdgcn_mfma_f32_16x16x32_bf16(fa0, fb0, d00, 0, 0, 0);
      d01 = __builtin_amdgcn_mfma_f32_16x16x32_bf16(fa0, fb1, d01, 0, 0, 0);
      d10 = __builtin_amdgcn_mfma_f32_16x16x32_bf16(fa1, fb0, d10, 0, 0, 0);
      d11 = __builtin_amdgcn_mfma_f32_16x16x32_bf16(fa1, fb1, d11, 0, 0, 0);
    }
    {
      const float b20 = sm.h2b[bn0], b21 = sm.h2b[bn1];
      const float4 wa = sm.w3t[bn0], wb = sm.w3t[bn1];
      #pragma unroll
      for (int mi = 0; mi < 2; ++mi) {
        #pragma unroll
        for (int j = 0; j < 4; ++j) {
          float x0 = (mi ? d10[j] : d00[j]) + b20; x0 = (x0 > 0.f) ? x0 : 0.2f * x0;
          float x1 = (mi ? d11[j] : d01[j]) + b21; x1 = (x1 > 0.f) ? x1 : 0.2f * x1;
          const float p0 = red16(x0 * wa.x + x1 * wb.x);
          const float p1 = red16(x0 * wa.y + x1 * wb.y);
          const float p2 = red16(x0 * wa.z + x1 * wb.z);
          if (lrow == 0) {
            const int r = wm * 32 + mi * 16 + lk8 * 4 + j;
            sm.part[r * 4 + wn] = make_float4(p0, p1, p2, 0.f);
          }
        }
      }
    }
    __syncthreads();

    // =========== Phase G3: out = unit(cur + delta) ===========
    if (tid < 64) {
      const int r = tid;
      const float4 qa = sm.part[r * 4 + 0], qb = sm.part[r * 4 + 1];
      const float4 qc = sm.part[r * 4 + 2], qd = sm.part[r * 4 + 3];
      const float ox = sm.cur[r][0] + qa.x + qb.x + qc.x + qd.x + sm.h3b[0];
      const float oy = sm.cur[r][1] + qa.y + qb.y + qc.y + qd.y + sm.h3b[1];
      const float oz = sm.cur[r][2] + qa.z + qb.z + qc.z + qd.z + sm.h3b[2];
      const float nn = sqrtf(ox * ox + oy * oy + oz * oz);
      const float iv = 1.f / fmaxf(nn, 1e-6f);
      const size_t o0 = (size_t)(rg0 + r) * 3;
      out[o0 + 0] = ox * iv; out[o0 + 1] = oy * iv; out[o0 + 2] = oz * iv;
    }
    __syncthreads();  // protect lf/h/cur/part before next tile
  }
}

extern "C" void kernel_launch(void* const* d_in, const int* in_sizes, int n_in,
                              void* d_out, int out_size, void* d_ws, size_t ws_size,
                              hipStream_t stream) {
  (void)in_sizes; (void)n_in; (void)out_size; (void)d_ws; (void)ws_size;
  const float* jf   = (const float*)d_in[0];
  // d_in[1] = pose_2d (unused by the reference)
  const float* p3   = (const float*)d_in[2];
  const float* az   = (const float*)d_in[3];
  const float* el   = (const float*)d_in[4];
  const float* p2d  = (const float*)d_in[5];
  const float* cow  = (const float*)d_in[6];
  const float* cob  = (const float*)d_in[7];
  const float* cog  = (const float*)d_in[8];
  const float* cobe = (const float*)d_in[9];
  const float* l2w  = (const float*)d_in[10];
  const float* l2b  = (const float*)d_in[11];
  const float* l2g  = (const float*)d_in[12];
  const float* l2be = (const float*)d_in[13];
  const float* vw   = (const float*)d_in[14];
  const float* vb   = (const float*)d_in[15];
  const float* w1   = (const float*)d_in[16];
  const float* h1b  = (const float*)d_in[17];
  const float* hg   = (const float*)d_in[18];
  const float* hbe  = (const float*)d_in[19];
  const float* w2   = (const float*)d_in[20];
  const float* h2b  = (const float*)d_in[21];
  const float* w3   = (const float*)d_in[22];
  const float* h3b  = (const float*)d_in[23];

  limb_kernel<<<dim3(256), dim3(NTHR), 0, stream>>>(
      jf, p3, az, el, p2d, cow, cob, cog, cobe,
      l2w, l2b, l2g, l2be, vw, vb,
      w1, h1b, hg, hbe, w2, h2b, w3, h3b, (float*)d_out);
}

// Round 2
// 808.985 us; speedup vs baseline: 1.4726x; 1.4726x over previous
//
#include <hip/hip_runtime.h>

// LimbOrientationPredictor fused kernel (MI355X / gfx950) — round 2
// M = 65536*14 = 917504 rows. Per row: build lf[256] features, h1(256->128)+LN+leaky,
// h2(128->128)+leaky, h3(128->3), out = unit(cur + delta).
// 256 persistent blocks x 512 threads (8 waves). Weights staged bf16 in LDS once/block.
// Round-2 changes: closed-form LN stats for l2/co (no shuffles), __sinf/__cosf for vf,
// readfirstlane scalarization of per-row uniform loads.

#define NTILES 14336   // 917504 / 64
#define NTHR   512
#define C2D    6.66662222251852f   // 1/(0.15+1e-6)

typedef __bf16 bf16x8 __attribute__((ext_vector_type(8)));
typedef float  f32x4  __attribute__((ext_vector_type(4)));

// PARENT-5 / CHILD-5 packed as 4-bit nibbles, l = 0..13
#define PARENT_PK 0x10106097863120ull
#define CHILD_PK  0x677671b9a85342ull

struct Smem {
  __bf16 W1[128][264];   // h1_w, rows padded 256->264 (2-way bank alias only)
  __bf16 W2[128][136];   // h2_w, 128->136
  __bf16 lf[64][264];    // feature tile [l2(64) co(32) pf(64) cf(64) vf(32)]
  __bf16 h [64][136];    // post-LN/leaky h1 output
  float4 w3t[128];       // h3_w transposed: w3t[c] = {w3[0][c], w3[1][c], w3[2][c], 0}
  float  h1b[128], hg[128], hbe[128], h2b[128];
  float  h3b[4];
  float  cur[64][4];     // unit bone vectors per row
  float4 part[256];      // [row][wave_n] partials (LN sums, then delta partials)
};

__device__ __forceinline__ float red16(float v) {  // sum across lanes sharing lane>>4
  v += __shfl_xor(v, 1, 64);
  v += __shfl_xor(v, 2, 64);
  v += __shfl_xor(v, 4, 64);
  v += __shfl_xor(v, 8, 64);
  return v;
}

__global__ __launch_bounds__(NTHR) void limb_kernel(
    const float* __restrict__ jf,  const float* __restrict__ p3g,
    const float* __restrict__ az,  const float* __restrict__ el,
    const float* __restrict__ p2d,
    const float* __restrict__ cow, const float* __restrict__ cob,
    const float* __restrict__ cog, const float* __restrict__ cobe,
    const float* __restrict__ l2w, const float* __restrict__ l2b,
    const float* __restrict__ l2g, const float* __restrict__ l2be,
    const float* __restrict__ vw,  const float* __restrict__ vb,
    const float* __restrict__ w1,  const float* __restrict__ h1bg,
    const float* __restrict__ hgg, const float* __restrict__ hbeg,
    const float* __restrict__ w2,  const float* __restrict__ h2bg,
    const float* __restrict__ w3,  const float* __restrict__ h3bg,
    float* __restrict__ out)
{
  __shared__ Smem sm;
  const int tid  = threadIdx.x;
  const int wave = tid >> 6;
  const int lane = tid & 63;

  // ---- one-time weight staging (fp32 global -> bf16 LDS) ----
  for (int i = tid; i < 128 * 256; i += NTHR) sm.W1[i >> 8][i & 255] = (__bf16)w1[i];
  for (int i = tid; i < 128 * 128; i += NTHR) sm.W2[i >> 7][i & 127] = (__bf16)w2[i];
  if (tid < 384) { int o = tid >> 7, c = tid & 127; ((float*)&sm.w3t[c])[o] = w3[tid]; }
  if (tid < 128) {
    sm.h1b[tid] = h1bg[tid]; sm.hg[tid] = hgg[tid];
    sm.hbe[tid] = hbeg[tid]; sm.h2b[tid] = h2bg[tid];
  }
  if (tid < 4) sm.h3b[tid] = (tid < 3) ? h3bg[tid] : 0.f;

  // ---- per-lane small-net params (l2 folded to 3 inputs: w2' = w2 + C2D*w3) ----
  const float lw0 = l2w[lane * 4 + 0], lw1 = l2w[lane * 4 + 1];
  const float lw2 = l2w[lane * 4 + 2] + C2D * l2w[lane * 4 + 3];
  const float lbv = l2b[lane], lgv = l2g[lane], lbev = l2be[lane];
  float cw0 = 0.f, cw1 = 0.f, cw2 = 0.f, cbv = 0.f, cgv = 0.f, cbev = 0.f;
  float vw0 = 0.f, vw2 = 0.f, vw3 = 0.f, vw4 = 0.f, vw6 = 0.f, v15 = 0.f, vbv = 0.f;
  if (lane < 32) {
    cw0 = cow[lane * 3 + 0]; cw1 = cow[lane * 3 + 1]; cw2 = cow[lane * 3 + 2];
    cbv = cob[lane]; cgv = cog[lane]; cbev = cobe[lane];
  } else {
    const int o = lane - 32;
    vw0 = vw[o * 7 + 0]; v15 = vw[o * 7 + 1] + vw[o * 7 + 5];
    vw2 = vw[o * 7 + 2]; vw3 = vw[o * 7 + 3];
    vw4 = vw[o * 7 + 4]; vw6 = vw[o * 7 + 6];
    vbv = vb[o];
  }

  // ---- closed-form LN stats for l2 (3-dim x = {f0, f1, L}) ----
  float lQxx, lQxy, lQxz, lQyy, lQyz, lQzz, lrx, lry, lrz, ls0, lmx, lmy, lmz, lmb;
  {
    float s1x = 0, s1y = 0, s1z = 0, sb = 0;
    float sxx = 0, sxy = 0, sxz = 0, syy = 0, syz = 0, szz = 0;
    float sbx = 0, sby = 0, sbz = 0, sbb = 0;
    for (int o = 0; o < 64; ++o) {
      const float w0 = l2w[o * 4 + 0], w1v = l2w[o * 4 + 1];
      const float w2v = l2w[o * 4 + 2] + C2D * l2w[o * 4 + 3];
      const float bo = l2b[o];
      s1x += w0; s1y += w1v; s1z += w2v; sb += bo;
      sxx += w0 * w0; sxy += w0 * w1v; sxz += w0 * w2v;
      syy += w1v * w1v; syz += w1v * w2v; szz += w2v * w2v;
      sbx += w0 * bo; sby += w1v * bo; sbz += w2v * bo; sbb += bo * bo;
    }
    const float i64 = 1.f / 64.f;
    lmx = s1x * i64; lmy = s1y * i64; lmz = s1z * i64; lmb = sb * i64;
    lQxx = sxx * i64 - lmx * lmx; lQxy = sxy * i64 - lmx * lmy; lQxz = sxz * i64 - lmx * lmz;
    lQyy = syy * i64 - lmy * lmy; lQyz = syz * i64 - lmy * lmz; lQzz = szz * i64 - lmz * lmz;
    lrx = sbx * i64 - lmx * lmb; lry = sby * i64 - lmy * lmb; lrz = sbz * i64 - lmz * lmb;
    ls0 = sbb * i64 - lmb * lmb;
  }
  // centered per-lane weights for l2
  const float lwc0 = lw0 - lmx, lwc1 = lw1 - lmy, lwc2 = lw2 - lmz, lbc = lbv - lmb;

  // ---- closed-form LN stats for co (3-dim x = {cx, cy, cz}) ----
  float cQxx, cQxy, cQxz, cQyy, cQyz, cQzz, crx, cry, crz, cs0, cmx, cmy, cmz, cmb;
  {
    float s1x = 0, s1y = 0, s1z = 0, sb = 0;
    float sxx = 0, sxy = 0, sxz = 0, syy = 0, syz = 0, szz = 0;
    float sbx = 0, sby = 0, sbz = 0, sbb = 0;
    for (int o = 0; o < 32; ++o) {
      const float w0 = cow[o * 3 + 0], w1v = cow[o * 3 + 1], w2v = cow[o * 3 + 2];
      const float bo = cob[o];
      s1x += w0; s1y += w1v; s1z += w2v; sb += bo;
      sxx += w0 * w0; sxy += w0 * w1v; sxz += w0 * w2v;
      syy += w1v * w1v; syz += w1v * w2v; szz += w2v * w2v;
      sbx += w0 * bo; sby += w1v * bo; sbz += w2v * bo; sbb += bo * bo;
    }
    const float i32 = 1.f / 32.f;
    cmx = s1x * i32; cmy = s1y * i32; cmz = s1z * i32; cmb = sb * i32;
    cQxx = sxx * i32 - cmx * cmx; cQxy = sxy * i32 - cmx * cmy; cQxz = sxz * i32 - cmx * cmz;
    cQyy = syy * i32 - cmy * cmy; cQyz = syz * i32 - cmy * cmz; cQzz = szz * i32 - cmz * cmz;
    crx = sbx * i32 - cmx * cmb; cry = sby * i32 - cmy * cmb; crz = sbz * i32 - cmz * cmb;
    cs0 = sbb * i32 - cmb * cmb;
  }
  const float cwc0 = cw0 - cmx, cwc1 = cw1 - cmy, cwc2 = cw2 - cmz, cbc = cbv - cmb;

  const int wm = wave >> 2, wn = wave & 3;  // 2 (M) x 4 (N) wave grid
  const int lrow = lane & 15, lk8 = lane >> 4;
  const int am0 = wm * 32 + lrow, am1 = am0 + 16;   // A rows
  const int bn0 = wn * 32 + lrow, bn1 = bn0 + 16;   // B cols

  __syncthreads();

  for (int tile = blockIdx.x; tile < NTILES; tile += gridDim.x) {
    const int rg0 = tile * 64;

    // =========== Phase F: build lf tile (each wave: 8 rows) ===========
    #pragma unroll 2
    for (int rr = 0; rr < 8; ++rr) {
      const int row = __builtin_amdgcn_readfirstlane(wave * 8 + rr);
      const unsigned rg = (unsigned)(rg0 + row);
      const unsigned b = rg / 14u;
      const int l = (int)(rg - b * 14u);
      const int p = 5 + (int)((PARENT_PK >> (4 * l)) & 15ull);
      const int c = 5 + (int)((CHILD_PK  >> (4 * l)) & 15ull);

      // issue the wide feature copies early (latency overlap)
      const float* jp = jf + ((size_t)b * 17 + (size_t)p) * 64;
      const float* jc = jf + ((size_t)b * 17 + (size_t)c) * 64;
      const float pfv = jp[lane];
      const float cfv = jc[lane];

      const float* p3 = p3g + (size_t)b * 51;
      const float dx = p3[c * 3 + 0] - p3[p * 3 + 0];
      const float dy = p3[c * 3 + 1] - p3[p * 3 + 1];
      const float dz = p3[c * 3 + 2] - p3[p * 3 + 2];
      const float cn = sqrtf(dx * dx + dy * dy + dz * dz);
      const float ci = 1.f / fmaxf(cn, 1e-6f);
      const float cx = dx * ci, cy = dy * ci, cz = dz * ci;
      if (lane == 0) { sm.cur[row][0] = cx; sm.cur[row][1] = cy; sm.cur[row][2] = cz; }

      const float* q2 = p2d + (size_t)b * 34;
      const float vx = q2[c * 2 + 0] - q2[p * 2 + 0];
      const float vy = q2[c * 2 + 1] - q2[p * 2 + 1];
      const float L  = sqrtf(vx * vx + vy * vy);
      const float il = 1.f / (L + 1e-6f);
      const float f0 = vx * il, f1 = vy * il;

      // l2: LN via closed-form variance (x = {f0, f1, L})
      {
        const float var = (lQxx * f0 + 2.f * (lQxy * f1 + lQxz * L) + 2.f * lrx) * f0 +
                          (lQyy * f1 + 2.f * lQyz * L + 2.f * lry) * f1 +
                          (lQzz * L + 2.f * lrz) * L + ls0;
        const float rs = rsqrtf(var + 1e-5f);
        const float a = lwc0 * f0 + lwc1 * f1 + lwc2 * L + lbc;  // already centered
        const float y = a * rs * lgv + lbev;
        sm.lf[row][lane] = (__bf16)fmaxf(y, 0.f);
      }

      if (lane < 32) {  // co: LN via closed-form variance (x = {cx, cy, cz})
        const float var = (cQxx * cx + 2.f * (cQxy * cy + cQxz * cz) + 2.f * crx) * cx +
                          (cQyy * cy + 2.f * cQyz * cz + 2.f * cry) * cy +
                          (cQzz * cz + 2.f * crz) * cz + cs0;
        const float rs = rsqrtf(var + 1e-5f);
        const float a = cwc0 * cx + cwc1 * cy + cwc2 * cz + cbc;
        const float y = a * rs * cgv + cbev;
        sm.lf[row][64 + lane] = (__bf16)fmaxf(y, 0.f);
      } else {          // vf: fast trig + relu
        const float azr = az[b] * 0.017453292519943295f;
        const float elr = el[b] * 0.017453292519943295f;
        const float sa = __sinf(azr), ca = __cosf(azr);
        const float se = __sinf(elr), ce = __cosf(elr);
        const float a = vw0 * (sa * ce) + v15 * se + vw2 * (ca * ce) +
                        vw3 * sa + vw4 * ca + vw6 * ce + vbv;
        sm.lf[row][224 + (lane - 32)] = (__bf16)fmaxf(a, 0.f);
      }

      // pf / cf stores (loads issued at top)
      sm.lf[row][96 + lane]  = (__bf16)pfv;
      sm.lf[row][160 + lane] = (__bf16)cfv;
    }
    __syncthreads();

    // =========== Phase G1: h1 = lf @ W1^T (64x256x128), LN + leaky ===========
    f32x4 a00 = {0.f, 0.f, 0.f, 0.f}, a01 = a00, a10 = a00, a11 = a00;
    #pragma unroll
    for (int kk = 0; kk < 8; ++kk) {
      const int ko = kk * 32 + lk8 * 8;
      const bf16x8 fa0 = *(const bf16x8*)&sm.lf[am0][ko];
      const bf16x8 fa1 = *(const bf16x8*)&sm.lf[am1][ko];
      const bf16x8 fb0 = *(const bf16x8*)&sm.W1[bn0][ko];
      const bf16x8 fb1 = *(const bf16x8*)&sm.W1[bn1][ko];
      a00 = __builtin_amdgcn_mfma_f32_16x16x32_bf16(fa0, fb0, a00, 0, 0, 0);
      a01 = __builtin_amdgcn_mfma_f32_16x16x32_bf16(fa0, fb1, a01, 0, 0, 0);
      a10 = __builtin_amdgcn_mfma_f32_16x16x32_bf16(fa1, fb0, a10, 0, 0, 0);
      a11 = __builtin_amdgcn_mfma_f32_16x16x32_bf16(fa1, fb1, a11, 0, 0, 0);
    }
    // bias + LN partial sums (wave covers 32 cols per row)
    const float hb0 = sm.h1b[bn0], hb1 = sm.h1b[bn1];
    float v00[4], v01[4], v10[4], v11[4];
    #pragma unroll
    for (int j = 0; j < 4; ++j) {
      v00[j] = a00[j] + hb0; v01[j] = a01[j] + hb1;
      v10[j] = a10[j] + hb0; v11[j] = a11[j] + hb1;
    }
    #pragma unroll
    for (int mi = 0; mi < 2; ++mi) {
      #pragma unroll
      for (int j = 0; j < 4; ++j) {
        const float x0 = mi ? v10[j] : v00[j];
        const float x1 = mi ? v11[j] : v01[j];
        const float ss = red16(x0 + x1);
        const float qq = red16(x0 * x0 + x1 * x1);
        if (lrow == 0) {
          const int r = wm * 32 + mi * 16 + lk8 * 4 + j;
          sm.part[r * 4 + wn] = make_float4(ss, qq, 0.f, 0.f);
        }
      }
    }
    __syncthreads();
    {
      const float g0 = sm.hg[bn0], g1 = sm.hg[bn1];
      const float e0 = sm.hbe[bn0], e1 = sm.hbe[bn1];
      #pragma unroll
      for (int mi = 0; mi < 2; ++mi) {
        #pragma unroll
        for (int j = 0; j < 4; ++j) {
          const int r = wm * 32 + mi * 16 + lk8 * 4 + j;
          const float4 pA = sm.part[r * 4 + 0], pB = sm.part[r * 4 + 1];
          const float4 pC = sm.part[r * 4 + 2], pD = sm.part[r * 4 + 3];
          const float mean = (pA.x + pB.x + pC.x + pD.x) * (1.f / 128.f);
          const float var  = (pA.y + pB.y + pC.y + pD.y) * (1.f / 128.f) - mean * mean;
          const float rs = rsqrtf(var + 1e-5f);
          const float x0 = mi ? v10[j] : v00[j];
          const float x1 = mi ? v11[j] : v01[j];
          float y0 = (x0 - mean) * rs * g0 + e0; y0 = (y0 > 0.f) ? y0 : 0.2f * y0;
          float y1 = (x1 - mean) * rs * g1 + e1; y1 = (y1 > 0.f) ? y1 : 0.2f * y1;
          sm.h[r][bn0] = (__bf16)y0;
          sm.h[r][bn1] = (__bf16)y1;
        }
      }
    }
    __syncthreads();

    // =========== Phase G2: h2 = h @ W2^T (64x128x128), leaky + fused h3 dot ===========
    f32x4 d00 = {0.f, 0.f, 0.f, 0.f}, d01 = d00, d10 = d00, d11 = d00;
    #pragma unroll
    for (int kk = 0; kk < 4; ++kk) {
      const int ko = kk * 32 + lk8 * 8;
      const bf16x8 fa0 = *(const bf16x8*)&sm.h[am0][ko];
      const bf16x8 fa1 = *(const bf16x8*)&sm.h[am1][ko];
      const bf16x8 fb0 = *(const bf16x8*)&sm.W2[bn0][ko];
      const bf16x8 fb1 = *(const bf16x8*)&sm.W2[bn1][ko];
      d00 = __builtin_amdgcn_mfma_f32_16x16x32_bf16(fa0, fb0, d00, 0, 0, 0);
      d01 = __builtin_amdgcn_mfma_f32_16x16x32_bf16(fa0, fb1, d01, 0, 0, 0);
      d10 = __builtin_amdgcn_mfma_f32_16x16x32_bf16(fa1, fb0, d10, 0, 0, 0);
      d11 = __builtin_amdgcn_mfma_f32_16x16x32_bf16(fa1, fb1, d11, 0, 0, 0);
    }
    {
      const float b20 = sm.h2b[bn0], b21 = sm.h2b[bn1];
      const float4 wa = sm.w3t[bn0], wb = sm.w3t[bn1];
      #pragma unroll
      for (int mi = 0; mi < 2; ++mi) {
        #pragma unroll
        for (int j = 0; j < 4; ++j) {
          float x0 = (mi ? d10[j] : d00[j]) + b20; x0 = (x0 > 0.f) ? x0 : 0.2f * x0;
          float x1 = (mi ? d11[j] : d01[j]) + b21; x1 = (x1 > 0.f) ? x1 : 0.2f * x1;
          const float p0 = red16(x0 * wa.x + x1 * wb.x);
          const float p1 = red16(x0 * wa.y + x1 * wb.y);
          const float p2 = red16(x0 * wa.z + x1 * wb.z);
          if (lrow == 0) {
            const int r = wm * 32 + mi * 16 + lk8 * 4 + j;
            sm.part[r * 4 + wn] = make_float4(p0, p1, p2, 0.f);
          }
        }
      }
    }
    __syncthreads();

    // =========== Phase G3: out = unit(cur + delta) ===========
    if (tid < 64) {
      const int r = tid;
      const float4 qa = sm.part[r * 4 + 0], qb = sm.part[r * 4 + 1];
      const float4 qc = sm.part[r * 4 + 2], qd = sm.part[r * 4 + 3];
      const float ox = sm.cur[r][0] + qa.x + qb.x + qc.x + qd.x + sm.h3b[0];
      const float oy = sm.cur[r][1] + qa.y + qb.y + qc.y + qd.y + sm.h3b[1];
      const float oz = sm.cur[r][2] + qa.z + qb.z + qc.z + qd.z + sm.h3b[2];
      const float nn = sqrtf(ox * ox + oy * oy + oz * oz);
      const float iv = 1.f / fmaxf(nn, 1e-6f);
      const size_t o0 = (size_t)(rg0 + r) * 3;
      out[o0 + 0] = ox * iv; out[o0 + 1] = oy * iv; out[o0 + 2] = oz * iv;
    }
    __syncthreads();  // protect lf/h/cur/part before next tile
  }
}

extern "C" void kernel_launch(void* const* d_in, const int* in_sizes, int n_in,
                              void* d_out, int out_size, void* d_ws, size_t ws_size,
                              hipStream_t stream) {
  (void)in_sizes; (void)n_in; (void)out_size; (void)d_ws; (void)ws_size;
  const float* jf   = (const float*)d_in[0];
  // d_in[1] = pose_2d (unused by the reference)
  const float* p3   = (const float*)d_in[2];
  const float* az   = (const float*)d_in[3];
  const float* el   = (const float*)d_in[4];
  const float* p2d  = (const float*)d_in[5];
  const float* cow  = (const float*)d_in[6];
  const float* cob  = (const float*)d_in[7];
  const float* cog  = (const float*)d_in[8];
  const float* cobe = (const float*)d_in[9];
  const float* l2w  = (const float*)d_in[10];
  const float* l2b  = (const float*)d_in[11];
  const float* l2g  = (const float*)d_in[12];
  const float* l2be = (const float*)d_in[13];
  const float* vw   = (const float*)d_in[14];
  const float* vb   = (const float*)d_in[15];
  const float* w1   = (const float*)d_in[16];
  const float* h1b  = (const float*)d_in[17];
  const float* hg   = (const float*)d_in[18];
  const float* hbe  = (const float*)d_in[19];
  const float* w2   = (const float*)d_in[20];
  const float* h2b  = (const float*)d_in[21];
  const float* w3   = (const float*)d_in[22];
  const float* h3b  = (const float*)d_in[23];

  limb_kernel<<<dim3(256), dim3(NTHR), 0, stream>>>(
      jf, p3, az, el, p2d, cow, cob, cog, cobe,
      l2w, l2b, l2g, l2be, vw, vb,
      w1, h1b, hg, hbe, w2, h2b, w3, h3b, (float*)d_out);
}

// Round 4
// 638.986 us; speedup vs baseline: 1.8644x; 1.2660x over previous
//
#include <hip/hip_runtime.h>

// LimbOrientationPredictor fused kernel (MI355X / gfx950) — round 4
// Round-4 change vs round 3: fix RFL() — __builtin_amdgcn_readfirstlane is int-typed;
// passing float implicitly TRUNCATED every closed-form LN statistic (r3 absmax 0.26).
// Now bit-cast through uint. Everything else identical to round 3:
//  * Phase A: lane-parallel scalar gather (wave 0) + float4 jf copies (all waves).
//  * W1/W2 pre-converted to bf16 frag-order in d_ws by prep_kernel; GEMM B-fragments
//    load straight from global (L2-resident). LDS ~64KB -> 2 blocks/CU.

#define NTHR   512
#define NBLK   512
#define NTILES 14336   // 917504 / 64
#define C2D    6.66662222251852f   // 1/(0.15+1e-6)

typedef __bf16 bf16x8 __attribute__((ext_vector_type(8)));
typedef __bf16 bf16x4 __attribute__((ext_vector_type(4)));
typedef float  f32x4  __attribute__((ext_vector_type(4)));

// PARENT-5 / CHILD-5 packed as 4-bit nibbles, l = 0..13
#define PARENT_PK 0x10106097863120ull
#define CHILD_PK  0x677671b9a85342ull

// ws layout (bytes): [0, 65536) w1f bf16 frag-ordered; [65536, 98304) w2f.
// w1f unit u (bf16x8): u = ((wn*8+kk)*2+f)*64 + lane;
//   col = wn*32 + f*16 + (lane&15), k = kk*32 + (lane>>4)*8 + j  -> w1[col*256+k]
// w2f unit v: v = ((wn*4+kk)*2+f)*64 + lane; k over 128 -> w2[col*128+k]

__global__ __launch_bounds__(256) void prep_kernel(
    const float* __restrict__ w1, const float* __restrict__ w2,
    __bf16* __restrict__ wsb)
{
  const int u = blockIdx.x * 256 + threadIdx.x;   // 24*256 = 6144 tasks
  if (u < 4096) {
    const int lane = u & 63, t = u >> 6;
    const int f = t & 1, kk = (t >> 1) & 7, wn = t >> 4;
    const int col = wn * 32 + f * 16 + (lane & 15);
    const int kb  = kk * 32 + (lane >> 4) * 8;
    __bf16* dst = wsb + (size_t)u * 8;
    #pragma unroll
    for (int j = 0; j < 8; ++j) dst[j] = (__bf16)w1[col * 256 + kb + j];
  } else if (u < 6144) {
    const int v = u - 4096;
    const int lane = v & 63, t = v >> 6;
    const int f = t & 1, kk = (t >> 1) & 3, wn = t >> 3;
    const int col = wn * 32 + f * 16 + (lane & 15);
    const int kb  = kk * 32 + (lane >> 4) * 8;
    __bf16* dst = wsb + 32768 + (size_t)v * 8;
    #pragma unroll
    for (int j = 0; j < 8; ++j) dst[j] = (__bf16)w2[col * 128 + kb + j];
  }
}

struct Smem {
  __bf16 lf[64][264];    // feature tile [l2(64) co(32) pf(64) cf(64) vf(32)], pad 8
  __bf16 h [64][136];    // post-LN/leaky h1 output, pad 8
  float  scal[64][13];   // 0..2 cx,cy,cz  3,4 f0,f1  5 L  6..11 view6
  float4 w3t[128];       // h3_w transposed
  float  h1b[128], hg[128], hbe[128], h2b[128];
  float  h3b[4];
  float4 part[256];      // [row][wave_n] partials
};

__device__ __forceinline__ float red16(float v) {  // sum across 16 lanes sharing lane>>4
  v += __shfl_xor(v, 1, 64);
  v += __shfl_xor(v, 2, 64);
  v += __shfl_xor(v, 4, 64);
  v += __shfl_xor(v, 8, 64);
  return v;
}

// Force wave-uniform float to SGPR. NOTE: __builtin_amdgcn_readfirstlane is
// int-typed — must BIT-CAST, not value-convert (r3 bug: implicit float->int
// truncation zeroed the LN stats).
__device__ __forceinline__ float RFL(float x) {
  return __uint_as_float((unsigned)__builtin_amdgcn_readfirstlane((int)__float_as_uint(x)));
}

__global__ __launch_bounds__(NTHR, 4) void limb_kernel(
    const float* __restrict__ jf,  const float* __restrict__ p3g,
    const float* __restrict__ az,  const float* __restrict__ el,
    const float* __restrict__ p2d,
    const float* __restrict__ cow, const float* __restrict__ cob,
    const float* __restrict__ cog, const float* __restrict__ cobe,
    const float* __restrict__ l2w, const float* __restrict__ l2b,
    const float* __restrict__ l2g, const float* __restrict__ l2be,
    const float* __restrict__ vw,  const float* __restrict__ vb,
    const float* __restrict__ h1bg, const float* __restrict__ hgg,
    const float* __restrict__ hbeg, const float* __restrict__ h2bg,
    const float* __restrict__ w3,  const float* __restrict__ h3bg,
    const __bf16* __restrict__ wsb,
    float* __restrict__ out)
{
  __shared__ Smem sm;
  const int tid  = threadIdx.x;
  const int wave = tid >> 6;
  const int lane = tid & 63;
  const int lrow = lane & 15, lk8 = lane >> 4;

  const bf16x8* __restrict__ w1f8 = (const bf16x8*)wsb;
  const bf16x8* __restrict__ w2f8 = (const bf16x8*)(wsb + 32768);

  // ---- one-time small staging ----
  if (tid < 384) { int o = tid >> 7, c = tid & 127; ((float*)&sm.w3t[c])[o] = w3[tid]; }
  if (tid < 128) {
    sm.h1b[tid] = h1bg[tid]; sm.hg[tid] = hgg[tid];
    sm.hbe[tid] = hbeg[tid]; sm.h2b[tid] = h2bg[tid];
  }
  if (tid < 4) sm.h3b[tid] = (tid < 3) ? h3bg[tid] : 0.f;

  // ---- closed-form LN stats (wave-uniform -> SGPR via RFL) ----
  float lQxx, lQxy2, lQxz2, lQyy, lQyz2, lQzz, lrx2, lry2, lrz2, ls0;
  float lmx, lmy, lmz, lmb;
  {
    float s1x = 0, s1y = 0, s1z = 0, sb = 0;
    float sxx = 0, sxy = 0, sxz = 0, syy = 0, syz = 0, szz = 0;
    float sbx = 0, sby = 0, sbz = 0, sbb = 0;
    for (int o = 0; o < 64; ++o) {
      const float w0 = l2w[o * 4 + 0], w1v = l2w[o * 4 + 1];
      const float w2v = l2w[o * 4 + 2] + C2D * l2w[o * 4 + 3];
      const float bo = l2b[o];
      s1x += w0; s1y += w1v; s1z += w2v; sb += bo;
      sxx += w0 * w0; sxy += w0 * w1v; sxz += w0 * w2v;
      syy += w1v * w1v; syz += w1v * w2v; szz += w2v * w2v;
      sbx += w0 * bo; sby += w1v * bo; sbz += w2v * bo; sbb += bo * bo;
    }
    const float i = 1.f / 64.f;
    lmx = RFL(s1x * i); lmy = RFL(s1y * i); lmz = RFL(s1z * i); lmb = RFL(sb * i);
    lQxx = RFL(sxx * i - lmx * lmx); lQxy2 = RFL(2.f * (sxy * i - lmx * lmy));
    lQxz2 = RFL(2.f * (sxz * i - lmx * lmz)); lQyy = RFL(syy * i - lmy * lmy);
    lQyz2 = RFL(2.f * (syz * i - lmy * lmz)); lQzz = RFL(szz * i - lmz * lmz);
    lrx2 = RFL(2.f * (sbx * i - lmx * lmb)); lry2 = RFL(2.f * (sby * i - lmy * lmb));
    lrz2 = RFL(2.f * (sbz * i - lmz * lmb)); ls0 = RFL(sbb * i - lmb * lmb);
  }
  float cQxx, cQxy2, cQxz2, cQyy, cQyz2, cQzz, crx2, cry2, crz2, cs0;
  float cmx, cmy, cmz, cmb;
  {
    float s1x = 0, s1y = 0, s1z = 0, sb = 0;
    float sxx = 0, sxy = 0, sxz = 0, syy = 0, syz = 0, szz = 0;
    float sbx = 0, sby = 0, sbz = 0, sbb = 0;
    for (int o = 0; o < 32; ++o) {
      const float w0 = cow[o * 3 + 0], w1v = cow[o * 3 + 1], w2v = cow[o * 3 + 2];
      const float bo = cob[o];
      s1x += w0; s1y += w1v; s1z += w2v; sb += bo;
      sxx += w0 * w0; sxy += w0 * w1v; sxz += w0 * w2v;
      syy += w1v * w1v; syz += w1v * w2v; szz += w2v * w2v;
      sbx += w0 * bo; sby += w1v * bo; sbz += w2v * bo; sbb += bo * bo;
    }
    const float i = 1.f / 32.f;
    cmx = RFL(s1x * i); cmy = RFL(s1y * i); cmz = RFL(s1z * i); cmb = RFL(sb * i);
    cQxx = RFL(sxx * i - cmx * cmx); cQxy2 = RFL(2.f * (sxy * i - cmx * cmy));
    cQxz2 = RFL(2.f * (sxz * i - cmx * cmz)); cQyy = RFL(syy * i - cmy * cmy);
    cQyz2 = RFL(2.f * (syz * i - cmy * cmz)); cQzz = RFL(szz * i - cmz * cmz);
    crx2 = RFL(2.f * (sbx * i - cmx * cmb)); cry2 = RFL(2.f * (sby * i - cmy * cmb));
    crz2 = RFL(2.f * (sbz * i - cmz * cmb)); cs0 = RFL(sbb * i - cmb * cmb);
  }

  // ---- per-lane small-net params ----
  const float lwc0 = l2w[lane * 4 + 0] - lmx;
  const float lwc1 = l2w[lane * 4 + 1] - lmy;
  const float lwc2 = (l2w[lane * 4 + 2] + C2D * l2w[lane * 4 + 3]) - lmz;
  const float lbc  = l2b[lane] - lmb;
  const float lgv  = l2g[lane], lbev = l2be[lane];
  // union regs: lane<32 -> co params (centered), lane>=32 -> vf params
  float u0, u1, u2, u3, u4, u5, u6;
  if (lane < 32) {
    u0 = cow[lane * 3 + 0] - cmx; u1 = cow[lane * 3 + 1] - cmy;
    u2 = cow[lane * 3 + 2] - cmz; u3 = cob[lane] - cmb;
    u4 = cog[lane]; u5 = cobe[lane]; u6 = 0.f;
  } else {
    const int o = lane - 32;
    u0 = vw[o * 7 + 0]; u1 = vw[o * 7 + 1] + vw[o * 7 + 5];
    u2 = vw[o * 7 + 2]; u3 = vw[o * 7 + 3];
    u4 = vw[o * 7 + 4]; u5 = vw[o * 7 + 6]; u6 = vb[o];
  }

  const int wm = wave >> 2, wn = wave & 3;  // 2 (M) x 4 (N) wave grid
  const int am0 = wm * 32 + lrow, am1 = am0 + 16;   // A rows
  const int bn0 = wn * 32 + lrow, bn1 = bn0 + 16;   // B cols (epilogue indexing)

  __syncthreads();

  for (int tile = blockIdx.x; tile < NTILES; tile += NBLK) {
    const int rg0 = tile * 64;

    // ========== Phase A: scalar gather (wave 0) + jf float4 copies (all waves) ==========
    float p3p0 = 0, p3p1 = 0, p3p2 = 0, p3c0 = 0, p3c1 = 0, p3c2 = 0;
    float q2p0 = 0, q2p1 = 0, q2c0 = 0, q2c1 = 0, sazv = 0, selv = 0;
    if (wave == 0) {  // lane = row: issue all 12 scalar loads concurrently
      const unsigned rg = (unsigned)(rg0 + lane);
      const unsigned b = rg / 14u;
      const int l = (int)(rg - b * 14u);
      const int p = 5 + (int)((PARENT_PK >> (4 * l)) & 15ull);
      const int c = 5 + (int)((CHILD_PK  >> (4 * l)) & 15ull);
      const float* p3 = p3g + (size_t)b * 51;
      p3p0 = p3[p * 3 + 0]; p3p1 = p3[p * 3 + 1]; p3p2 = p3[p * 3 + 2];
      p3c0 = p3[c * 3 + 0]; p3c1 = p3[c * 3 + 1]; p3c2 = p3[c * 3 + 2];
      const float* q2 = p2d + (size_t)b * 34;
      q2p0 = q2[p * 2 + 0]; q2p1 = q2[p * 2 + 1];
      q2c0 = q2[c * 2 + 0]; q2c1 = q2[c * 2 + 1];
      sazv = az[b]; selv = el[b];
    }
    // jf copies: 128 row-joint tasks, 16/wave, 4 lane-group tasks per round
    #pragma unroll
    for (int round = 0; round < 4; ++round) {
      const int task = wave * 16 + round * 4 + lk8;
      const int row = task >> 1, half = task & 1;
      const unsigned rg = (unsigned)(rg0 + row);
      const unsigned b = rg / 14u;
      const int l = (int)(rg - b * 14u);
      const int j = half ? 5 + (int)((CHILD_PK >> (4 * l)) & 15ull)
                         : 5 + (int)((PARENT_PK >> (4 * l)) & 15ull);
      const float4 v = *(const float4*)(jf + ((size_t)b * 17 + (size_t)j) * 64 + lrow * 4);
      bf16x4 o; o[0] = (__bf16)v.x; o[1] = (__bf16)v.y; o[2] = (__bf16)v.z; o[3] = (__bf16)v.w;
      *(bf16x4*)&sm.lf[row][(half ? 160 : 96) + lrow * 4] = o;
    }
    if (wave == 0) {  // scalar compute + store (loads already in flight)
      const int row = lane;
      const float dx = p3c0 - p3p0, dy = p3c1 - p3p1, dz = p3c2 - p3p2;
      const float ci = 1.f / fmaxf(sqrtf(dx * dx + dy * dy + dz * dz), 1e-6f);
      const float cx = dx * ci, cy = dy * ci, cz = dz * ci;
      const float vx = q2c0 - q2p0, vy = q2c1 - q2p1;
      const float L  = sqrtf(vx * vx + vy * vy);
      const float il = 1.f / (L + 1e-6f);
      const float azr = sazv * 0.017453292519943295f;
      const float elr = selv * 0.017453292519943295f;
      const float sa = __sinf(azr), ca = __cosf(azr);
      const float se = __sinf(elr), ce = __cosf(elr);
      sm.scal[row][0] = cx; sm.scal[row][1] = cy; sm.scal[row][2] = cz;
      sm.scal[row][3] = vx * il; sm.scal[row][4] = vy * il; sm.scal[row][5] = L;
      sm.scal[row][6] = sa * ce; sm.scal[row][7] = se; sm.scal[row][8] = ca * ce;
      sm.scal[row][9] = sa; sm.scal[row][10] = ca; sm.scal[row][11] = ce;
    }
    __syncthreads();

    // ========== Phase B: expand (no global loads, no trig) ==========
    #pragma unroll 2
    for (int rr = 0; rr < 8; ++rr) {
      const int row = wave * 8 + rr;
      const float cx = sm.scal[row][0], cy = sm.scal[row][1], cz = sm.scal[row][2];
      const float f0 = sm.scal[row][3], f1 = sm.scal[row][4], Lv = sm.scal[row][5];
      // l2 (all 64 lanes)
      {
        const float var = lQxx * f0 * f0 + lQyy * f1 * f1 + lQzz * Lv * Lv +
                          lQxy2 * f0 * f1 + lQxz2 * f0 * Lv + lQyz2 * f1 * Lv +
                          lrx2 * f0 + lry2 * f1 + lrz2 * Lv + ls0;
        const float rs = rsqrtf(var + 1e-5f);
        const float a = lwc0 * f0 + lwc1 * f1 + lwc2 * Lv + lbc;
        sm.lf[row][lane] = (__bf16)fmaxf(a * rs * lgv + lbev, 0.f);
      }
      if (lane < 32) {  // co
        const float var = cQxx * cx * cx + cQyy * cy * cy + cQzz * cz * cz +
                          cQxy2 * cx * cy + cQxz2 * cx * cz + cQyz2 * cy * cz +
                          crx2 * cx + cry2 * cy + crz2 * cz + cs0;
        const float rs = rsqrtf(var + 1e-5f);
        const float a = u0 * cx + u1 * cy + u2 * cz + u3;
        sm.lf[row][64 + lane] = (__bf16)fmaxf(a * rs * u4 + u5, 0.f);
      } else {          // vf
        const float a = u0 * sm.scal[row][6] + u1 * sm.scal[row][7] +
                        u2 * sm.scal[row][8] + u3 * sm.scal[row][9] +
                        u4 * sm.scal[row][10] + u5 * sm.scal[row][11] + u6;
        sm.lf[row][224 + (lane - 32)] = (__bf16)fmaxf(a, 0.f);
      }
    }
    __syncthreads();

    // ========== G1: h1 = lf @ W1^T (64x256x128), LN + leaky ==========
    f32x4 a00 = {0.f, 0.f, 0.f, 0.f}, a01 = a00, a10 = a00, a11 = a00;
    #pragma unroll
    for (int kk = 0; kk < 8; ++kk) {
      const int ko = kk * 32 + lk8 * 8;
      const bf16x8 fa0 = *(const bf16x8*)&sm.lf[am0][ko];
      const bf16x8 fa1 = *(const bf16x8*)&sm.lf[am1][ko];
      const bf16x8 fb0 = w1f8[((wn * 8 + kk) * 2 + 0) * 64 + lane];
      const bf16x8 fb1 = w1f8[((wn * 8 + kk) * 2 + 1) * 64 + lane];
      a00 = __builtin_amdgcn_mfma_f32_16x16x32_bf16(fa0, fb0, a00, 0, 0, 0);
      a01 = __builtin_amdgcn_mfma_f32_16x16x32_bf16(fa0, fb1, a01, 0, 0, 0);
      a10 = __builtin_amdgcn_mfma_f32_16x16x32_bf16(fa1, fb0, a10, 0, 0, 0);
      a11 = __builtin_amdgcn_mfma_f32_16x16x32_bf16(fa1, fb1, a11, 0, 0, 0);
    }
    const float hb0 = sm.h1b[bn0], hb1 = sm.h1b[bn1];
    float v00[4], v01[4], v10[4], v11[4];
    #pragma unroll
    for (int j = 0; j < 4; ++j) {
      v00[j] = a00[j] + hb0; v01[j] = a01[j] + hb1;
      v10[j] = a10[j] + hb0; v11[j] = a11[j] + hb1;
    }
    #pragma unroll
    for (int mi = 0; mi < 2; ++mi) {
      #pragma unroll
      for (int j = 0; j < 4; ++j) {
        const float x0 = mi ? v10[j] : v00[j];
        const float x1 = mi ? v11[j] : v01[j];
        const float ss = red16(x0 + x1);
        const float qq = red16(x0 * x0 + x1 * x1);
        if (lrow == 0) {
          const int r = wm * 32 + mi * 16 + lk8 * 4 + j;
          sm.part[r * 4 + wn] = make_float4(ss, qq, 0.f, 0.f);
        }
      }
    }
    __syncthreads();
    {
      const float g0 = sm.hg[bn0], g1 = sm.hg[bn1];
      const float e0 = sm.hbe[bn0], e1 = sm.hbe[bn1];
      #pragma unroll
      for (int mi = 0; mi < 2; ++mi) {
        #pragma unroll
        for (int j = 0; j < 4; ++j) {
          const int r = wm * 32 + mi * 16 + lk8 * 4 + j;
          const float4 pA = sm.part[r * 4 + 0], pB = sm.part[r * 4 + 1];
          const float4 pC = sm.part[r * 4 + 2], pD = sm.part[r * 4 + 3];
          const float mean = (pA.x + pB.x + pC.x + pD.x) * (1.f / 128.f);
          const float var  = (pA.y + pB.y + pC.y + pD.y) * (1.f / 128.f) - mean * mean;
          const float rs = rsqrtf(var + 1e-5f);
          const float x0 = mi ? v10[j] : v00[j];
          const float x1 = mi ? v11[j] : v01[j];
          float y0 = (x0 - mean) * rs * g0 + e0; y0 = (y0 > 0.f) ? y0 : 0.2f * y0;
          float y1 = (x1 - mean) * rs * g1 + e1; y1 = (y1 > 0.f) ? y1 : 0.2f * y1;
          sm.h[r][bn0] = (__bf16)y0;
          sm.h[r][bn1] = (__bf16)y1;
        }
      }
    }
    __syncthreads();

    // ========== G2: h2 = h @ W2^T (64x128x128), leaky + fused h3 dot ==========
    f32x4 d00 = {0.f, 0.f, 0.f, 0.f}, d01 = d00, d10 = d00, d11 = d00;
    #pragma unroll
    for (int kk = 0; kk < 4; ++kk) {
      const int ko = kk * 32 + lk8 * 8;
      const bf16x8 fa0 = *(const bf16x8*)&sm.h[am0][ko];
      const bf16x8 fa1 = *(const bf16x8*)&sm.h[am1][ko];
      const bf16x8 fb0 = w2f8[((wn * 4 + kk) * 2 + 0) * 64 + lane];
      const bf16x8 fb1 = w2f8[((wn * 4 + kk) * 2 + 1) * 64 + lane];
      d00 = __builtin_amdgcn_mfma_f32_16x16x32_bf16(fa0, fb0, d00, 0, 0, 0);
      d01 = __builtin_amdgcn_mfma_f32_16x16x32_bf16(fa0, fb1, d01, 0, 0, 0);
      d10 = __builtin_amdgcn_mfma_f32_16x16x32_bf16(fa1, fb0, d10, 0, 0, 0);
      d11 = __builtin_amdgcn_mfma_f32_16x16x32_bf16(fa1, fb1, d11, 0, 0, 0);
    }
    {
      const float b20 = sm.h2b[bn0], b21 = sm.h2b[bn1];
      const float4 wa = sm.w3t[bn0], wb = sm.w3t[bn1];
      #pragma unroll
      for (int mi = 0; mi < 2; ++mi) {
        #pragma unroll
        for (int j = 0; j < 4; ++j) {
          float x0 = (mi ? d10[j] : d00[j]) + b20; x0 = (x0 > 0.f) ? x0 : 0.2f * x0;
          float x1 = (mi ? d11[j] : d01[j]) + b21; x1 = (x1 > 0.f) ? x1 : 0.2f * x1;
          const float p0 = red16(x0 * wa.x + x1 * wb.x);
          const float p1 = red16(x0 * wa.y + x1 * wb.y);
          const float p2 = red16(x0 * wa.z + x1 * wb.z);
          if (lrow == 0) {
            const int r = wm * 32 + mi * 16 + lk8 * 4 + j;
            sm.part[r * 4 + wn] = make_float4(p0, p1, p2, 0.f);
          }
        }
      }
    }
    __syncthreads();

    // ========== G3: out = unit(cur + delta) ==========
    if (tid < 64) {
      const int r = tid;
      const float4 qa = sm.part[r * 4 + 0], qb = sm.part[r * 4 + 1];
      const float4 qc = sm.part[r * 4 + 2], qd = sm.part[r * 4 + 3];
      const float ox = sm.scal[r][0] + qa.x + qb.x + qc.x + qd.x + sm.h3b[0];
      const float oy = sm.scal[r][1] + qa.y + qb.y + qc.y + qd.y + sm.h3b[1];
      const float oz = sm.scal[r][2] + qa.z + qb.z + qc.z + qd.z + sm.h3b[2];
      const float nn = sqrtf(ox * ox + oy * oy + oz * oz);
      const float iv = 1.f / fmaxf(nn, 1e-6f);
      const size_t o0 = (size_t)(rg0 + r) * 3;
      out[o0 + 0] = ox * iv; out[o0 + 1] = oy * iv; out[o0 + 2] = oz * iv;
    }
    __syncthreads();  // protect lf/h/scal/part before next tile
  }
}

extern "C" void kernel_launch(void* const* d_in, const int* in_sizes, int n_in,
                              void* d_out, int out_size, void* d_ws, size_t ws_size,
                              hipStream_t stream) {
  (void)in_sizes; (void)n_in; (void)out_size; (void)ws_size;
  const float* jf   = (const float*)d_in[0];
  // d_in[1] = pose_2d (unused by the reference)
  const float* p3   = (const float*)d_in[2];
  const float* az   = (const float*)d_in[3];
  const float* el   = (const float*)d_in[4];
  const float* p2d  = (const float*)d_in[5];
  const float* cow  = (const float*)d_in[6];
  const float* cob  = (const float*)d_in[7];
  const float* cog  = (const float*)d_in[8];
  const float* cobe = (const float*)d_in[9];
  const float* l2w  = (const float*)d_in[10];
  const float* l2b  = (const float*)d_in[11];
  const float* l2g  = (const float*)d_in[12];
  const float* l2be = (const float*)d_in[13];
  const float* vw   = (const float*)d_in[14];
  const float* vb   = (const float*)d_in[15];
  const float* w1   = (const float*)d_in[16];
  const float* h1b  = (const float*)d_in[17];
  const float* hg   = (const float*)d_in[18];
  const float* hbe  = (const float*)d_in[19];
  const float* w2   = (const float*)d_in[20];
  const float* h2b  = (const float*)d_in[21];
  const float* w3   = (const float*)d_in[22];
  const float* h3b  = (const float*)d_in[23];

  __bf16* wsb = (__bf16*)d_ws;

  prep_kernel<<<dim3(24), dim3(256), 0, stream>>>(w1, w2, wsb);
  limb_kernel<<<dim3(NBLK), dim3(NTHR), 0, stream>>>(
      jf, p3, az, el, p2d, cow, cob, cog, cobe,
      l2w, l2b, l2g, l2be, vw, vb,
      h1b, hg, hbe, h2b, w3, h3b, wsb, (float*)d_out);
}

// Round 5
// 584.033 us; speedup vs baseline: 2.0398x; 1.0941x over previous
//
#include <hip/hip_runtime.h>

// LimbOrientationPredictor fused kernel (MI355X / gfx950) — round 5
// Round-5 changes vs round 4 (which re-read 96KB of weights from global EVERY tile,
// FETCH_SIZE 1.1GB, latency exposed in the MFMA loop):
//  * W1 fragments hoisted into REGISTERS once per wave (64 VGPR, loop-invariant).
//  * W2 fragments staged into LDS once per block (32KB); G2 reads via ds_read_b128.
//  * h-tile ALIASED into lf buffer (barrier-protected) to keep LDS at 78.9KB -> 2 blocks/CU.
//  * LN variance quadratics (row-uniform) moved to wave-0 Phase A (were computed 64x redundantly).

#define NTHR   512
#define NBLK   512
#define NTILES 14336   // 917504 / 64
#define C2D    6.66662222251852f   // 1/(0.15+1e-6)

typedef __bf16 bf16x8 __attribute__((ext_vector_type(8)));
typedef __bf16 bf16x4 __attribute__((ext_vector_type(4)));
typedef float  f32x4  __attribute__((ext_vector_type(4)));

// PARENT-5 / CHILD-5 packed as 4-bit nibbles, l = 0..13
#define PARENT_PK 0x10106097863120ull
#define CHILD_PK  0x677671b9a85342ull

// ws layout (bf16 elems): [0, 32768) w1f frag-ordered; [32768, 49152) w2f.
// w1f unit u (bf16x8): u = ((wn*8+kk)*2+f)*64 + lane;
//   col = wn*32 + f*16 + (lane&15), k = kk*32 + (lane>>4)*8 + j  -> w1[col*256+k]
// w2f unit v: v = ((wn*4+kk)*2+f)*64 + lane; k over 128 -> w2[col*128+k]

__global__ __launch_bounds__(256) void prep_kernel(
    const float* __restrict__ w1, const float* __restrict__ w2,
    __bf16* __restrict__ wsb)
{
  const int u = blockIdx.x * 256 + threadIdx.x;   // 24*256 = 6144 tasks
  if (u < 4096) {
    const int lane = u & 63, t = u >> 6;
    const int f = t & 1, kk = (t >> 1) & 7, wn = t >> 4;
    const int col = wn * 32 + f * 16 + (lane & 15);
    const int kb  = kk * 32 + (lane >> 4) * 8;
    __bf16* dst = wsb + (size_t)u * 8;
    #pragma unroll
    for (int j = 0; j < 8; ++j) dst[j] = (__bf16)w1[col * 256 + kb + j];
  } else if (u < 6144) {
    const int v = u - 4096;
    const int lane = v & 63, t = v >> 6;
    const int f = t & 1, kk = (t >> 1) & 3, wn = t >> 3;
    const int col = wn * 32 + f * 16 + (lane & 15);
    const int kb  = kk * 32 + (lane >> 4) * 8;
    __bf16* dst = wsb + 32768 + (size_t)v * 8;
    #pragma unroll
    for (int j = 0; j < 8; ++j) dst[j] = (__bf16)w2[col * 128 + kb + j];
  }
}

struct Smem {
  __bf16 lf[64][264];    // 33792B feature tile [l2 co pf cf vf]; h-tile ALIASES cols 0..135 after G1
  __bf16 w2f[16384];     // 32768B W2 frag-ordered (unit v at w2f[v*8])
  float  scal[64][16];   // 0..2 cx,cy,cz  3,4 f0,f1  5 L  6..11 view6  12 rs_l2  13 rs_co
  float4 w3t[128];       // h3_w transposed
  float  h1b[128], hg[128], hbe[128], h2b[128];
  float  h3b[4];
  float4 part[256];      // [row][wave_n] partials
};                        // total 78864 B -> 2 blocks/CU

__device__ __forceinline__ float red16(float v) {  // sum across 16 lanes sharing lane>>4
  v += __shfl_xor(v, 1, 64);
  v += __shfl_xor(v, 2, 64);
  v += __shfl_xor(v, 4, 64);
  v += __shfl_xor(v, 8, 64);
  return v;
}

// Force wave-uniform float to SGPR (bit-cast: readfirstlane is int-typed).
__device__ __forceinline__ float RFL(float x) {
  return __uint_as_float((unsigned)__builtin_amdgcn_readfirstlane((int)__float_as_uint(x)));
}

__global__ __launch_bounds__(NTHR, 4) void limb_kernel(
    const float* __restrict__ jf,  const float* __restrict__ p3g,
    const float* __restrict__ az,  const float* __restrict__ el,
    const float* __restrict__ p2d,
    const float* __restrict__ cow, const float* __restrict__ cob,
    const float* __restrict__ cog, const float* __restrict__ cobe,
    const float* __restrict__ l2w, const float* __restrict__ l2b,
    const float* __restrict__ l2g, const float* __restrict__ l2be,
    const float* __restrict__ vw,  const float* __restrict__ vb,
    const float* __restrict__ h1bg, const float* __restrict__ hgg,
    const float* __restrict__ hbeg, const float* __restrict__ h2bg,
    const float* __restrict__ w3,  const float* __restrict__ h3bg,
    const __bf16* __restrict__ wsb,
    float* __restrict__ out)
{
  __shared__ Smem sm;
  const int tid  = threadIdx.x;
  const int wave = tid >> 6;
  const int lane = tid & 63;
  const int lrow = lane & 15, lk8 = lane >> 4;
  const int wm = wave >> 2, wn = wave & 3;  // 2 (M) x 4 (N) wave grid
  const int am0 = wm * 32 + lrow, am1 = am0 + 16;   // A rows
  const int bn0 = wn * 32 + lrow, bn1 = bn0 + 16;   // B cols (epilogue indexing)

  const bf16x8* __restrict__ w1f8 = (const bf16x8*)wsb;

  // ---- one-time staging: w2f -> LDS (32KB), small params -> LDS ----
  {
    const uint4* src = (const uint4*)(wsb + 32768);
    uint4* dst = (uint4*)sm.w2f;
    for (int i = tid; i < 2048; i += NTHR) dst[i] = src[i];
  }
  if (tid < 384) { int o = tid >> 7, c = tid & 127; ((float*)&sm.w3t[c])[o] = w3[tid]; }
  if (tid < 128) {
    sm.h1b[tid] = h1bg[tid]; sm.hg[tid] = hgg[tid];
    sm.hbe[tid] = hbeg[tid]; sm.h2b[tid] = h2bg[tid];
  }
  if (tid < 4) sm.h3b[tid] = (tid < 3) ? h3bg[tid] : 0.f;

  // ---- W1 fragments -> registers (loop-invariant, 64 VGPR) ----
  bf16x8 fw1[8][2];
  #pragma unroll
  for (int kk = 0; kk < 8; ++kk) {
    fw1[kk][0] = w1f8[((wn * 8 + kk) * 2 + 0) * 64 + lane];
    fw1[kk][1] = w1f8[((wn * 8 + kk) * 2 + 1) * 64 + lane];
  }

  // ---- closed-form LN stats (wave-uniform -> SGPR via RFL) ----
  float lQxx, lQxy2, lQxz2, lQyy, lQyz2, lQzz, lrx2, lry2, lrz2, ls0;
  float lmx, lmy, lmz, lmb;
  {
    float s1x = 0, s1y = 0, s1z = 0, sb = 0;
    float sxx = 0, sxy = 0, sxz = 0, syy = 0, syz = 0, szz = 0;
    float sbx = 0, sby = 0, sbz = 0, sbb = 0;
    for (int o = 0; o < 64; ++o) {
      const float w0 = l2w[o * 4 + 0], w1v = l2w[o * 4 + 1];
      const float w2v = l2w[o * 4 + 2] + C2D * l2w[o * 4 + 3];
      const float bo = l2b[o];
      s1x += w0; s1y += w1v; s1z += w2v; sb += bo;
      sxx += w0 * w0; sxy += w0 * w1v; sxz += w0 * w2v;
      syy += w1v * w1v; syz += w1v * w2v; szz += w2v * w2v;
      sbx += w0 * bo; sby += w1v * bo; sbz += w2v * bo; sbb += bo * bo;
    }
    const float i = 1.f / 64.f;
    lmx = RFL(s1x * i); lmy = RFL(s1y * i); lmz = RFL(s1z * i); lmb = RFL(sb * i);
    lQxx = RFL(sxx * i - lmx * lmx); lQxy2 = RFL(2.f * (sxy * i - lmx * lmy));
    lQxz2 = RFL(2.f * (sxz * i - lmx * lmz)); lQyy = RFL(syy * i - lmy * lmy);
    lQyz2 = RFL(2.f * (syz * i - lmy * lmz)); lQzz = RFL(szz * i - lmz * lmz);
    lrx2 = RFL(2.f * (sbx * i - lmx * lmb)); lry2 = RFL(2.f * (sby * i - lmy * lmb));
    lrz2 = RFL(2.f * (sbz * i - lmz * lmb)); ls0 = RFL(sbb * i - lmb * lmb);
  }
  float cQxx, cQxy2, cQxz2, cQyy, cQyz2, cQzz, crx2, cry2, crz2, cs0;
  float cmx, cmy, cmz, cmb;
  {
    float s1x = 0, s1y = 0, s1z = 0, sb = 0;
    float sxx = 0, sxy = 0, sxz = 0, syy = 0, syz = 0, szz = 0;
    float sbx = 0, sby = 0, sbz = 0, sbb = 0;
    for (int o = 0; o < 32; ++o) {
      const float w0 = cow[o * 3 + 0], w1v = cow[o * 3 + 1], w2v = cow[o * 3 + 2];
      const float bo = cob[o];
      s1x += w0; s1y += w1v; s1z += w2v; sb += bo;
      sxx += w0 * w0; sxy += w0 * w1v; sxz += w0 * w2v;
      syy += w1v * w1v; syz += w1v * w2v; szz += w2v * w2v;
      sbx += w0 * bo; sby += w1v * bo; sbz += w2v * bo; sbb += bo * bo;
    }
    const float i = 1.f / 32.f;
    cmx = RFL(s1x * i); cmy = RFL(s1y * i); cmz = RFL(s1z * i); cmb = RFL(sb * i);
    cQxx = RFL(sxx * i - cmx * cmx); cQxy2 = RFL(2.f * (sxy * i - cmx * cmy));
    cQxz2 = RFL(2.f * (sxz * i - cmx * cmz)); cQyy = RFL(syy * i - cmy * cmy);
    cQyz2 = RFL(2.f * (syz * i - cmy * cmz)); cQzz = RFL(szz * i - cmz * cmz);
    crx2 = RFL(2.f * (sbx * i - cmx * cmb)); cry2 = RFL(2.f * (sby * i - cmy * cmb));
    crz2 = RFL(2.f * (sbz * i - cmz * cmb)); cs0 = RFL(sbb * i - cmb * cmb);
  }

  // ---- per-lane small-net params ----
  const float lwc0 = l2w[lane * 4 + 0] - lmx;
  const float lwc1 = l2w[lane * 4 + 1] - lmy;
  const float lwc2 = (l2w[lane * 4 + 2] + C2D * l2w[lane * 4 + 3]) - lmz;
  const float lbc  = l2b[lane] - lmb;
  const float lgv  = l2g[lane], lbev = l2be[lane];
  // union regs: lane<32 -> co params (centered), lane>=32 -> vf params
  float u0, u1, u2, u3, u4, u5, u6;
  if (lane < 32) {
    u0 = cow[lane * 3 + 0] - cmx; u1 = cow[lane * 3 + 1] - cmy;
    u2 = cow[lane * 3 + 2] - cmz; u3 = cob[lane] - cmb;
    u4 = cog[lane]; u5 = cobe[lane]; u6 = 0.f;
  } else {
    const int o = lane - 32;
    u0 = vw[o * 7 + 0]; u1 = vw[o * 7 + 1] + vw[o * 7 + 5];
    u2 = vw[o * 7 + 2]; u3 = vw[o * 7 + 3];
    u4 = vw[o * 7 + 4]; u5 = vw[o * 7 + 6]; u6 = vb[o];
  }

  __syncthreads();

  for (int tile = blockIdx.x; tile < NTILES; tile += NBLK) {
    const int rg0 = tile * 64;

    // ========== Phase A: scalar gather (wave 0) + jf float4 copies (all waves) ==========
    float p3p0 = 0, p3p1 = 0, p3p2 = 0, p3c0 = 0, p3c1 = 0, p3c2 = 0;
    float q2p0 = 0, q2p1 = 0, q2c0 = 0, q2c1 = 0, sazv = 0, selv = 0;
    if (wave == 0) {  // lane = row: issue all 12 scalar loads concurrently
      const unsigned rg = (unsigned)(rg0 + lane);
      const unsigned b = rg / 14u;
      const int l = (int)(rg - b * 14u);
      const int p = 5 + (int)((PARENT_PK >> (4 * l)) & 15ull);
      const int c = 5 + (int)((CHILD_PK  >> (4 * l)) & 15ull);
      const float* p3 = p3g + (size_t)b * 51;
      p3p0 = p3[p * 3 + 0]; p3p1 = p3[p * 3 + 1]; p3p2 = p3[p * 3 + 2];
      p3c0 = p3[c * 3 + 0]; p3c1 = p3[c * 3 + 1]; p3c2 = p3[c * 3 + 2];
      const float* q2 = p2d + (size_t)b * 34;
      q2p0 = q2[p * 2 + 0]; q2p1 = q2[p * 2 + 1];
      q2c0 = q2[c * 2 + 0]; q2c1 = q2[c * 2 + 1];
      sazv = az[b]; selv = el[b];
    }
    // jf copies: 128 row-joint tasks, 16/wave, 4 lane-group tasks per round
    #pragma unroll
    for (int round = 0; round < 4; ++round) {
      const int task = wave * 16 + round * 4 + lk8;
      const int row = task >> 1, half = task & 1;
      const unsigned rg = (unsigned)(rg0 + row);
      const unsigned b = rg / 14u;
      const int l = (int)(rg - b * 14u);
      const int j = half ? 5 + (int)((CHILD_PK >> (4 * l)) & 15ull)
                         : 5 + (int)((PARENT_PK >> (4 * l)) & 15ull);
      const float4 v = *(const float4*)(jf + ((size_t)b * 17 + (size_t)j) * 64 + lrow * 4);
      bf16x4 o; o[0] = (__bf16)v.x; o[1] = (__bf16)v.y; o[2] = (__bf16)v.z; o[3] = (__bf16)v.w;
      *(bf16x4*)&sm.lf[row][(half ? 160 : 96) + lrow * 4] = o;
    }
    if (wave == 0) {  // scalar compute + store (loads already in flight)
      const int row = lane;
      const float dx = p3c0 - p3p0, dy = p3c1 - p3p1, dz = p3c2 - p3p2;
      const float ci = 1.f / fmaxf(sqrtf(dx * dx + dy * dy + dz * dz), 1e-6f);
      const float cx = dx * ci, cy = dy * ci, cz = dz * ci;
      const float vx = q2c0 - q2p0, vy = q2c1 - q2p1;
      const float L  = sqrtf(vx * vx + vy * vy);
      const float il = 1.f / (L + 1e-6f);
      const float f0 = vx * il, f1 = vy * il;
      const float azr = sazv * 0.017453292519943295f;
      const float elr = selv * 0.017453292519943295f;
      const float sa = __sinf(azr), ca = __cosf(azr);
      const float se = __sinf(elr), ce = __cosf(elr);
      // row-uniform LN variances (were computed 64x redundantly in Phase B)
      const float vl = lQxx * f0 * f0 + lQyy * f1 * f1 + lQzz * L * L +
                       lQxy2 * f0 * f1 + lQxz2 * f0 * L + lQyz2 * f1 * L +
                       lrx2 * f0 + lry2 * f1 + lrz2 * L + ls0;
      const float vc = cQxx * cx * cx + cQyy * cy * cy + cQzz * cz * cz +
                       cQxy2 * cx * cy + cQxz2 * cx * cz + cQyz2 * cy * cz +
                       crx2 * cx + cry2 * cy + crz2 * cz + cs0;
      sm.scal[row][0] = cx; sm.scal[row][1] = cy; sm.scal[row][2] = cz;
      sm.scal[row][3] = f0; sm.scal[row][4] = f1; sm.scal[row][5] = L;
      sm.scal[row][6] = sa * ce; sm.scal[row][7] = se; sm.scal[row][8] = ca * ce;
      sm.scal[row][9] = sa; sm.scal[row][10] = ca; sm.scal[row][11] = ce;
      sm.scal[row][12] = rsqrtf(vl + 1e-5f);
      sm.scal[row][13] = rsqrtf(vc + 1e-5f);
    }
    __syncthreads();

    // ========== Phase B: expand (no global loads, no trig, no quadratics) ==========
    #pragma unroll 2
    for (int rr = 0; rr < 8; ++rr) {
      const int row = wave * 8 + rr;
      const float cx = sm.scal[row][0], cy = sm.scal[row][1], cz = sm.scal[row][2];
      const float f0 = sm.scal[row][3], f1 = sm.scal[row][4], Lv = sm.scal[row][5];
      const float rs2 = sm.scal[row][12], rsc = sm.scal[row][13];
      // l2 (all 64 lanes)
      {
        const float a = lwc0 * f0 + lwc1 * f1 + lwc2 * Lv + lbc;
        sm.lf[row][lane] = (__bf16)fmaxf(a * rs2 * lgv + lbev, 0.f);
      }
      if (lane < 32) {  // co
        const float a = u0 * cx + u1 * cy + u2 * cz + u3;
        sm.lf[row][64 + lane] = (__bf16)fmaxf(a * rsc * u4 + u5, 0.f);
      } else {          // vf
        const float a = u0 * sm.scal[row][6] + u1 * sm.scal[row][7] +
                        u2 * sm.scal[row][8] + u3 * sm.scal[row][9] +
                        u4 * sm.scal[row][10] + u5 * sm.scal[row][11] + u6;
        sm.lf[row][224 + (lane - 32)] = (__bf16)fmaxf(a, 0.f);
      }
    }
    __syncthreads();

    // ========== G1: h1 = lf @ W1^T (64x256x128), LN + leaky ==========
    f32x4 a00 = {0.f, 0.f, 0.f, 0.f}, a01 = a00, a10 = a00, a11 = a00;
    #pragma unroll
    for (int kk = 0; kk < 8; ++kk) {
      const int ko = kk * 32 + lk8 * 8;
      const bf16x8 fa0 = *(const bf16x8*)&sm.lf[am0][ko];
      const bf16x8 fa1 = *(const bf16x8*)&sm.lf[am1][ko];
      a00 = __builtin_amdgcn_mfma_f32_16x16x32_bf16(fa0, fw1[kk][0], a00, 0, 0, 0);
      a01 = __builtin_amdgcn_mfma_f32_16x16x32_bf16(fa0, fw1[kk][1], a01, 0, 0, 0);
      a10 = __builtin_amdgcn_mfma_f32_16x16x32_bf16(fa1, fw1[kk][0], a10, 0, 0, 0);
      a11 = __builtin_amdgcn_mfma_f32_16x16x32_bf16(fa1, fw1[kk][1], a11, 0, 0, 0);
    }
    const float hb0 = sm.h1b[bn0], hb1 = sm.h1b[bn1];
    float v00[4], v01[4], v10[4], v11[4];
    #pragma unroll
    for (int j = 0; j < 4; ++j) {
      v00[j] = a00[j] + hb0; v01[j] = a01[j] + hb1;
      v10[j] = a10[j] + hb0; v11[j] = a11[j] + hb1;
    }
    #pragma unroll
    for (int mi = 0; mi < 2; ++mi) {
      #pragma unroll
      for (int j = 0; j < 4; ++j) {
        const float x0 = mi ? v10[j] : v00[j];
        const float x1 = mi ? v11[j] : v01[j];
        const float ss = red16(x0 + x1);
        const float qq = red16(x0 * x0 + x1 * x1);
        if (lrow == 0) {
          const int r = wm * 32 + mi * 16 + lk8 * 4 + j;
          sm.part[r * 4 + wn] = make_float4(ss, qq, 0.f, 0.f);
        }
      }
    }
    __syncthreads();
    // LN-apply + h write (h ALIASES lf cols 0..127 — all lf MFMA reads done at the barrier)
    {
      const float g0 = sm.hg[bn0], g1 = sm.hg[bn1];
      const float e0 = sm.hbe[bn0], e1 = sm.hbe[bn1];
      #pragma unroll
      for (int mi = 0; mi < 2; ++mi) {
        #pragma unroll
        for (int j = 0; j < 4; ++j) {
          const int r = wm * 32 + mi * 16 + lk8 * 4 + j;
          const float4 pA = sm.part[r * 4 + 0], pB = sm.part[r * 4 + 1];
          const float4 pC = sm.part[r * 4 + 2], pD = sm.part[r * 4 + 3];
          const float mean = (pA.x + pB.x + pC.x + pD.x) * (1.f / 128.f);
          const float var  = (pA.y + pB.y + pC.y + pD.y) * (1.f / 128.f) - mean * mean;
          const float rs = rsqrtf(var + 1e-5f);
          const float x0 = mi ? v10[j] : v00[j];
          const float x1 = mi ? v11[j] : v01[j];
          float y0 = (x0 - mean) * rs * g0 + e0; y0 = (y0 > 0.f) ? y0 : 0.2f * y0;
          float y1 = (x1 - mean) * rs * g1 + e1; y1 = (y1 > 0.f) ? y1 : 0.2f * y1;
          sm.lf[r][bn0] = (__bf16)y0;   // h-tile aliased into lf
          sm.lf[r][bn1] = (__bf16)y1;
        }
      }
    }
    __syncthreads();

    // ========== G2: h2 = h @ W2^T (64x128x128), leaky + fused h3 dot ==========
    f32x4 d00 = {0.f, 0.f, 0.f, 0.f}, d01 = d00, d10 = d00, d11 = d00;
    #pragma unroll
    for (int kk = 0; kk < 4; ++kk) {
      const int ko = kk * 32 + lk8 * 8;
      const bf16x8 fa0 = *(const bf16x8*)&sm.lf[am0][ko];   // h-tile
      const bf16x8 fa1 = *(const bf16x8*)&sm.lf[am1][ko];
      const bf16x8 fb0 = *(const bf16x8*)&sm.w2f[(((wn * 4 + kk) * 2 + 0) * 64 + lane) * 8];
      const bf16x8 fb1 = *(const bf16x8*)&sm.w2f[(((wn * 4 + kk) * 2 + 1) * 64 + lane) * 8];
      d00 = __builtin_amdgcn_mfma_f32_16x16x32_bf16(fa0, fb0, d00, 0, 0, 0);
      d01 = __builtin_amdgcn_mfma_f32_16x16x32_bf16(fa0, fb1, d01, 0, 0, 0);
      d10 = __builtin_amdgcn_mfma_f32_16x16x32_bf16(fa1, fb0, d10, 0, 0, 0);
      d11 = __builtin_amdgcn_mfma_f32_16x16x32_bf16(fa1, fb1, d11, 0, 0, 0);
    }
    {
      const float b20 = sm.h2b[bn0], b21 = sm.h2b[bn1];
      const float4 wa = sm.w3t[bn0], wb = sm.w3t[bn1];
      #pragma unroll
      for (int mi = 0; mi < 2; ++mi) {
        #pragma unroll
        for (int j = 0; j < 4; ++j) {
          float x0 = (mi ? d10[j] : d00[j]) + b20; x0 = (x0 > 0.f) ? x0 : 0.2f * x0;
          float x1 = (mi ? d11[j] : d01[j]) + b21; x1 = (x1 > 0.f) ? x1 : 0.2f * x1;
          const float p0 = red16(x0 * wa.x + x1 * wb.x);
          const float p1 = red16(x0 * wa.y + x1 * wb.y);
          const float p2 = red16(x0 * wa.z + x1 * wb.z);
          if (lrow == 0) {
            const int r = wm * 32 + mi * 16 + lk8 * 4 + j;
            sm.part[r * 4 + wn] = make_float4(p0, p1, p2, 0.f);
          }
        }
      }
    }
    __syncthreads();

    // ========== G3: out = unit(cur + delta) ==========
    if (tid < 64) {
      const int r = tid;
      const float4 qa = sm.part[r * 4 + 0], qb = sm.part[r * 4 + 1];
      const float4 qc = sm.part[r * 4 + 2], qd = sm.part[r * 4 + 3];
      const float ox = sm.scal[r][0] + qa.x + qb.x + qc.x + qd.x + sm.h3b[0];
      const float oy = sm.scal[r][1] + qa.y + qb.y + qc.y + qd.y + sm.h3b[1];
      const float oz = sm.scal[r][2] + qa.z + qb.z + qc.z + qd.z + sm.h3b[2];
      const float nn = sqrtf(ox * ox + oy * oy + oz * oz);
      const float iv = 1.f / fmaxf(nn, 1e-6f);
      const size_t o0 = (size_t)(rg0 + r) * 3;
      out[o0 + 0] = ox * iv; out[o0 + 1] = oy * iv; out[o0 + 2] = oz * iv;
    }
    __syncthreads();  // protect lf/scal/part before next tile
  }
}

extern "C" void kernel_launch(void* const* d_in, const int* in_sizes, int n_in,
                              void* d_out, int out_size, void* d_ws, size_t ws_size,
                              hipStream_t stream) {
  (void)in_sizes; (void)n_in; (void)out_size; (void)ws_size;
  const float* jf   = (const float*)d_in[0];
  // d_in[1] = pose_2d (unused by the reference)
  const float* p3   = (const float*)d_in[2];
  const float* az   = (const float*)d_in[3];
  const float* el   = (const float*)d_in[4];
  const float* p2d  = (const float*)d_in[5];
  const float* cow  = (const float*)d_in[6];
  const float* cob  = (const float*)d_in[7];
  const float* cog  = (const float*)d_in[8];
  const float* cobe = (const float*)d_in[9];
  const float* l2w  = (const float*)d_in[10];
  const float* l2b  = (const float*)d_in[11];
  const float* l2g  = (const float*)d_in[12];
  const float* l2be = (const float*)d_in[13];
  const float* vw   = (const float*)d_in[14];
  const float* vb   = (const float*)d_in[15];
  const float* w1   = (const float*)d_in[16];
  const float* h1b  = (const float*)d_in[17];
  const float* hg   = (const float*)d_in[18];
  const float* hbe  = (const float*)d_in[19];
  const float* w2   = (const float*)d_in[20];
  const float* h2b  = (const float*)d_in[21];
  const float* w3   = (const float*)d_in[22];
  const float* h3b  = (const float*)d_in[23];

  __bf16* wsb = (__bf16*)d_ws;

  prep_kernel<<<dim3(24), dim3(256), 0, stream>>>(w1, w2, wsb);
  limb_kernel<<<dim3(NBLK), dim3(NTHR), 0, stream>>>(
      jf, p3, az, el, p2d, cow, cob, cog, cobe,
      l2w, l2b, l2g, l2be, vw, vb,
      h1b, hg, hbe, h2b, w3, h3b, wsb, (float*)d_out);
}

// Round 6
// 544.393 us; speedup vs baseline: 2.1883x; 1.0728x over previous
//
#include <hip/hip_runtime.h>

// LimbOrientationPredictor fused kernel (MI355X / gfx950) — round 6
// Round-6 changes vs round 5 (where VGPR_Count=64 proved the compiler re-loaded W1
// fragments from global INSIDE the MFMA loop every tile — L2/HBM latency in the chain):
//  * W1 AND W2 both staged in LDS (96KB, frag-ordered, conflict-free ds_read_b128).
//  * ONE 1024-thread block per CU (16 waves, 4M x 4N wave grid, 64-row tile).
//    Same 16 waves/CU as r5, but weights never leave the CU and per-wave epilogue halves.
//  * launch_bounds(1024,4) — required for 4 waves/SIMD (VGPR <= 128).

#define NTHR   1024
#define NBLK   256
#define NTILES 14336   // 917504 / 64
#define C2D    6.66662222251852f   // 1/(0.15+1e-6)

typedef __bf16 bf16x8 __attribute__((ext_vector_type(8)));
typedef __bf16 bf16x4 __attribute__((ext_vector_type(4)));
typedef float  f32x4  __attribute__((ext_vector_type(4)));

// PARENT-5 / CHILD-5 packed as 4-bit nibbles, l = 0..13
#define PARENT_PK 0x10106097863120ull
#define CHILD_PK  0x677671b9a85342ull

// ws layout (bf16 elems): [0, 32768) w1f frag-ordered; [32768, 49152) w2f.
// w1f unit u (bf16x8): u = ((wn*8+kk)*2+f)*64 + lane;
//   col = wn*32 + f*16 + (lane&15), k = kk*32 + (lane>>4)*8 + j  -> w1[col*256+k]
// w2f unit v: v = ((wn*4+kk)*2+f)*64 + lane; k over 128 -> w2[col*128+k]

__global__ __launch_bounds__(256) void prep_kernel(
    const float* __restrict__ w1, const float* __restrict__ w2,
    __bf16* __restrict__ wsb)
{
  const int u = blockIdx.x * 256 + threadIdx.x;   // 24*256 = 6144 tasks
  if (u < 4096) {
    const int lane = u & 63, t = u >> 6;
    const int f = t & 1, kk = (t >> 1) & 7, wn = t >> 4;
    const int col = wn * 32 + f * 16 + (lane & 15);
    const int kb  = kk * 32 + (lane >> 4) * 8;
    __bf16* dst = wsb + (size_t)u * 8;
    #pragma unroll
    for (int j = 0; j < 8; ++j) dst[j] = (__bf16)w1[col * 256 + kb + j];
  } else if (u < 6144) {
    const int v = u - 4096;
    const int lane = v & 63, t = v >> 6;
    const int f = t & 1, kk = (t >> 1) & 3, wn = t >> 3;
    const int col = wn * 32 + f * 16 + (lane & 15);
    const int kb  = kk * 32 + (lane >> 4) * 8;
    __bf16* dst = wsb + 32768 + (size_t)v * 8;
    #pragma unroll
    for (int j = 0; j < 8; ++j) dst[j] = (__bf16)w2[col * 128 + kb + j];
  }
}

struct Smem {
  __bf16 w1f[32768];     // 65536B W1 frag-ordered
  __bf16 w2f[16384];     // 32768B W2 frag-ordered
  __bf16 lf[64][264];    // 33792B feature tile; h-tile ALIASES cols 0..135 after G1
  float  scal[64][16];   // 0..2 cx,cy,cz  3,4 f0,f1  5 L  6..11 view6  12 rs_l2  13 rs_co
  float4 w3t[128];       // h3_w transposed
  float  h1b[128], hg[128], hbe[128], h2b[128];
  float  h3b[4];
  float4 part[256];      // [row][wave_n] partials
};                        // total ~144.4KB -> 1 block/CU, 16 waves

__device__ __forceinline__ float red16(float v) {  // sum across 16 lanes sharing lane>>4
  v += __shfl_xor(v, 1, 64);
  v += __shfl_xor(v, 2, 64);
  v += __shfl_xor(v, 4, 64);
  v += __shfl_xor(v, 8, 64);
  return v;
}

// Force wave-uniform float to SGPR (bit-cast: readfirstlane is int-typed).
__device__ __forceinline__ float RFL(float x) {
  return __uint_as_float((unsigned)__builtin_amdgcn_readfirstlane((int)__float_as_uint(x)));
}

__global__ __launch_bounds__(NTHR, 4) void limb_kernel(
    const float* __restrict__ jf,  const float* __restrict__ p3g,
    const float* __restrict__ az,  const float* __restrict__ el,
    const float* __restrict__ p2d,
    const float* __restrict__ cow, const float* __restrict__ cob,
    const float* __restrict__ cog, const float* __restrict__ cobe,
    const float* __restrict__ l2w, const float* __restrict__ l2b,
    const float* __restrict__ l2g, const float* __restrict__ l2be,
    const float* __restrict__ vw,  const float* __restrict__ vb,
    const float* __restrict__ h1bg, const float* __restrict__ hgg,
    const float* __restrict__ hbeg, const float* __restrict__ h2bg,
    const float* __restrict__ w3,  const float* __restrict__ h3bg,
    const __bf16* __restrict__ wsb,
    float* __restrict__ out)
{
  __shared__ Smem sm;
  const int tid  = threadIdx.x;
  const int wave = tid >> 6;
  const int lane = tid & 63;
  const int lrow = lane & 15, lk8 = lane >> 4;
  const int wm = wave >> 2, wn = wave & 3;          // 4 (M) x 4 (N) wave grid
  const int am0 = wm * 16 + lrow;                   // A rows (16 per wave)
  const int bn0 = wn * 32 + lrow, bn1 = bn0 + 16;   // B cols (epilogue indexing)

  // ---- one-time staging: w1f+w2f -> LDS (96KB), small params -> LDS ----
  {
    const uint4* s1 = (const uint4*)wsb;            // 4096 uint4
    uint4* d1 = (uint4*)sm.w1f;
    for (int i = tid; i < 4096; i += NTHR) d1[i] = s1[i];
    const uint4* s2 = (const uint4*)(wsb + 32768);  // 2048 uint4
    uint4* d2 = (uint4*)sm.w2f;
    for (int i = tid; i < 2048; i += NTHR) d2[i] = s2[i];
  }
  if (tid < 384) { int o = tid >> 7, c = tid & 127; ((float*)&sm.w3t[c])[o] = w3[tid]; }
  if (tid < 128) {
    sm.h1b[tid] = h1bg[tid]; sm.hg[tid] = hgg[tid];
    sm.hbe[tid] = hbeg[tid]; sm.h2b[tid] = h2bg[tid];
  }
  if (tid < 4) sm.h3b[tid] = (tid < 3) ? h3bg[tid] : 0.f;

  // ---- closed-form LN stats (wave-uniform -> SGPR via RFL) ----
  float lQxx, lQxy2, lQxz2, lQyy, lQyz2, lQzz, lrx2, lry2, lrz2, ls0;
  float lmx, lmy, lmz, lmb;
  {
    float s1x = 0, s1y = 0, s1z = 0, sb = 0;
    float sxx = 0, sxy = 0, sxz = 0, syy = 0, syz = 0, szz = 0;
    float sbx = 0, sby = 0, sbz = 0, sbb = 0;
    for (int o = 0; o < 64; ++o) {
      const float w0 = l2w[o * 4 + 0], w1v = l2w[o * 4 + 1];
      const float w2v = l2w[o * 4 + 2] + C2D * l2w[o * 4 + 3];
      const float bo = l2b[o];
      s1x += w0; s1y += w1v; s1z += w2v; sb += bo;
      sxx += w0 * w0; sxy += w0 * w1v; sxz += w0 * w2v;
      syy += w1v * w1v; syz += w1v * w2v; szz += w2v * w2v;
      sbx += w0 * bo; sby += w1v * bo; sbz += w2v * bo; sbb += bo * bo;
    }
    const float i = 1.f / 64.f;
    lmx = RFL(s1x * i); lmy = RFL(s1y * i); lmz = RFL(s1z * i); lmb = RFL(sb * i);
    lQxx = RFL(sxx * i - lmx * lmx); lQxy2 = RFL(2.f * (sxy * i - lmx * lmy));
    lQxz2 = RFL(2.f * (sxz * i - lmx * lmz)); lQyy = RFL(syy * i - lmy * lmy);
    lQyz2 = RFL(2.f * (syz * i - lmy * lmz)); lQzz = RFL(szz * i - lmz * lmz);
    lrx2 = RFL(2.f * (sbx * i - lmx * lmb)); lry2 = RFL(2.f * (sby * i - lmy * lmb));
    lrz2 = RFL(2.f * (sbz * i - lmz * lmb)); ls0 = RFL(sbb * i - lmb * lmb);
  }
  float cQxx, cQxy2, cQxz2, cQyy, cQyz2, cQzz, crx2, cry2, crz2, cs0;
  float cmx, cmy, cmz, cmb;
  {
    float s1x = 0, s1y = 0, s1z = 0, sb = 0;
    float sxx = 0, sxy = 0, sxz = 0, syy = 0, syz = 0, szz = 0;
    float sbx = 0, sby = 0, sbz = 0, sbb = 0;
    for (int o = 0; o < 32; ++o) {
      const float w0 = cow[o * 3 + 0], w1v = cow[o * 3 + 1], w2v = cow[o * 3 + 2];
      const float bo = cob[o];
      s1x += w0; s1y += w1v; s1z += w2v; sb += bo;
      sxx += w0 * w0; sxy += w0 * w1v; sxz += w0 * w2v;
      syy += w1v * w1v; syz += w1v * w2v; szz += w2v * w2v;
      sbx += w0 * bo; sby += w1v * bo; sbz += w2v * bo; sbb += bo * bo;
    }
    const float i = 1.f / 32.f;
    cmx = RFL(s1x * i); cmy = RFL(s1y * i); cmz = RFL(s1z * i); cmb = RFL(sb * i);
    cQxx = RFL(sxx * i - cmx * cmx); cQxy2 = RFL(2.f * (sxy * i - cmx * cmy));
    cQxz2 = RFL(2.f * (sxz * i - cmx * cmz)); cQyy = RFL(syy * i - cmy * cmy);
    cQyz2 = RFL(2.f * (syz * i - cmy * cmz)); cQzz = RFL(szz * i - cmz * cmz);
    crx2 = RFL(2.f * (sbx * i - cmx * cmb)); cry2 = RFL(2.f * (sby * i - cmy * cmb));
    crz2 = RFL(2.f * (sbz * i - cmz * cmb)); cs0 = RFL(sbb * i - cmb * cmb);
  }

  // ---- per-lane small-net params ----
  const float lwc0 = l2w[lane * 4 + 0] - lmx;
  const float lwc1 = l2w[lane * 4 + 1] - lmy;
  const float lwc2 = (l2w[lane * 4 + 2] + C2D * l2w[lane * 4 + 3]) - lmz;
  const float lbc  = l2b[lane] - lmb;
  const float lgv  = l2g[lane], lbev = l2be[lane];
  // union regs: lane<32 -> co params (centered), lane>=32 -> vf params
  float u0, u1, u2, u3, u4, u5, u6;
  if (lane < 32) {
    u0 = cow[lane * 3 + 0] - cmx; u1 = cow[lane * 3 + 1] - cmy;
    u2 = cow[lane * 3 + 2] - cmz; u3 = cob[lane] - cmb;
    u4 = cog[lane]; u5 = cobe[lane]; u6 = 0.f;
  } else {
    const int o = lane - 32;
    u0 = vw[o * 7 + 0]; u1 = vw[o * 7 + 1] + vw[o * 7 + 5];
    u2 = vw[o * 7 + 2]; u3 = vw[o * 7 + 3];
    u4 = vw[o * 7 + 4]; u5 = vw[o * 7 + 6]; u6 = vb[o];
  }

  __syncthreads();

  for (int tile = blockIdx.x; tile < NTILES; tile += NBLK) {
    const int rg0 = tile * 64;

    // ========== Phase A: scalar gather (wave 0) + jf float4 copies (all waves) ==========
    float p3p0 = 0, p3p1 = 0, p3p2 = 0, p3c0 = 0, p3c1 = 0, p3c2 = 0;
    float q2p0 = 0, q2p1 = 0, q2c0 = 0, q2c1 = 0, sazv = 0, selv = 0;
    if (wave == 0) {  // lane = row: issue all 12 scalar loads concurrently
      const unsigned rg = (unsigned)(rg0 + lane);
      const unsigned b = rg / 14u;
      const int l = (int)(rg - b * 14u);
      const int p = 5 + (int)((PARENT_PK >> (4 * l)) & 15ull);
      const int c = 5 + (int)((CHILD_PK  >> (4 * l)) & 15ull);
      const float* p3 = p3g + (size_t)b * 51;
      p3p0 = p3[p * 3 + 0]; p3p1 = p3[p * 3 + 1]; p3p2 = p3[p * 3 + 2];
      p3c0 = p3[c * 3 + 0]; p3c1 = p3[c * 3 + 1]; p3c2 = p3[c * 3 + 2];
      const float* q2 = p2d + (size_t)b * 34;
      q2p0 = q2[p * 2 + 0]; q2p1 = q2[p * 2 + 1];
      q2c0 = q2[c * 2 + 0]; q2c1 = q2[c * 2 + 1];
      sazv = az[b]; selv = el[b];
    }
    // jf copies: 128 row-joint tasks, 8/wave, 4 lane-group tasks per round, 2 rounds
    #pragma unroll
    for (int round = 0; round < 2; ++round) {
      const int task = wave * 8 + round * 4 + lk8;
      const int row = task >> 1, half = task & 1;
      const unsigned rg = (unsigned)(rg0 + row);
      const unsigned b = rg / 14u;
      const int l = (int)(rg - b * 14u);
      const int j = half ? 5 + (int)((CHILD_PK >> (4 * l)) & 15ull)
                         : 5 + (int)((PARENT_PK >> (4 * l)) & 15ull);
      const float4 v = *(const float4*)(jf + ((size_t)b * 17 + (size_t)j) * 64 + lrow * 4);
      bf16x4 o; o[0] = (__bf16)v.x; o[1] = (__bf16)v.y; o[2] = (__bf16)v.z; o[3] = (__bf16)v.w;
      *(bf16x4*)&sm.lf[row][(half ? 160 : 96) + lrow * 4] = o;
    }
    if (wave == 0) {  // scalar compute + store (loads already in flight)
      const int row = lane;
      const float dx = p3c0 - p3p0, dy = p3c1 - p3p1, dz = p3c2 - p3p2;
      const float ci = 1.f / fmaxf(sqrtf(dx * dx + dy * dy + dz * dz), 1e-6f);
      const float cx = dx * ci, cy = dy * ci, cz = dz * ci;
      const float vx = q2c0 - q2p0, vy = q2c1 - q2p1;
      const float L  = sqrtf(vx * vx + vy * vy);
      const float il = 1.f / (L + 1e-6f);
      const float f0 = vx * il, f1 = vy * il;
      const float azr = sazv * 0.017453292519943295f;
      const float elr = selv * 0.017453292519943295f;
      const float sa = __sinf(azr), ca = __cosf(azr);
      const float se = __sinf(elr), ce = __cosf(elr);
      // row-uniform LN variances
      const float vl = lQxx * f0 * f0 + lQyy * f1 * f1 + lQzz * L * L +
                       lQxy2 * f0 * f1 + lQxz2 * f0 * L + lQyz2 * f1 * L +
                       lrx2 * f0 + lry2 * f1 + lrz2 * L + ls0;
      const float vc = cQxx * cx * cx + cQyy * cy * cy + cQzz * cz * cz +
                       cQxy2 * cx * cy + cQxz2 * cx * cz + cQyz2 * cy * cz +
                       crx2 * cx + cry2 * cy + crz2 * cz + cs0;
      sm.scal[row][0] = cx; sm.scal[row][1] = cy; sm.scal[row][2] = cz;
      sm.scal[row][3] = f0; sm.scal[row][4] = f1; sm.scal[row][5] = L;
      sm.scal[row][6] = sa * ce; sm.scal[row][7] = se; sm.scal[row][8] = ca * ce;
      sm.scal[row][9] = sa; sm.scal[row][10] = ca; sm.scal[row][11] = ce;
      sm.scal[row][12] = rsqrtf(vl + 1e-5f);
      sm.scal[row][13] = rsqrtf(vc + 1e-5f);
    }
    __syncthreads();

    // ========== Phase B: expand (4 rows/wave, no loads, no trig, no quadratics) ==========
    #pragma unroll
    for (int rr = 0; rr < 4; ++rr) {
      const int row = wave * 4 + rr;
      const float cx = sm.scal[row][0], cy = sm.scal[row][1], cz = sm.scal[row][2];
      const float f0 = sm.scal[row][3], f1 = sm.scal[row][4], Lv = sm.scal[row][5];
      const float rs2 = sm.scal[row][12], rsc = sm.scal[row][13];
      // l2 (all 64 lanes)
      {
        const float a = lwc0 * f0 + lwc1 * f1 + lwc2 * Lv + lbc;
        sm.lf[row][lane] = (__bf16)fmaxf(a * rs2 * lgv + lbev, 0.f);
      }
      if (lane < 32) {  // co
        const float a = u0 * cx + u1 * cy + u2 * cz + u3;
        sm.lf[row][64 + lane] = (__bf16)fmaxf(a * rsc * u4 + u5, 0.f);
      } else {          // vf
        const float a = u0 * sm.scal[row][6] + u1 * sm.scal[row][7] +
                        u2 * sm.scal[row][8] + u3 * sm.scal[row][9] +
                        u4 * sm.scal[row][10] + u5 * sm.scal[row][11] + u6;
        sm.lf[row][224 + (lane - 32)] = (__bf16)fmaxf(a, 0.f);
      }
    }
    __syncthreads();

    // ========== G1: h1 = lf @ W1^T (64x256x128), LN + leaky ==========
    f32x4 a0 = {0.f, 0.f, 0.f, 0.f}, a1 = a0;
    #pragma unroll
    for (int kk = 0; kk < 8; ++kk) {
      const int ko = kk * 32 + lk8 * 8;
      const bf16x8 fa  = *(const bf16x8*)&sm.lf[am0][ko];
      const bf16x8 fb0 = *(const bf16x8*)&sm.w1f[(((wn * 8 + kk) * 2 + 0) * 64 + lane) * 8];
      const bf16x8 fb1 = *(const bf16x8*)&sm.w1f[(((wn * 8 + kk) * 2 + 1) * 64 + lane) * 8];
      a0 = __builtin_amdgcn_mfma_f32_16x16x32_bf16(fa, fb0, a0, 0, 0, 0);
      a1 = __builtin_amdgcn_mfma_f32_16x16x32_bf16(fa, fb1, a1, 0, 0, 0);
    }
    const float hb0 = sm.h1b[bn0], hb1 = sm.h1b[bn1];
    float v0[4], v1[4];
    #pragma unroll
    for (int j = 0; j < 4; ++j) { v0[j] = a0[j] + hb0; v1[j] = a1[j] + hb1; }
    #pragma unroll
    for (int j = 0; j < 4; ++j) {
      const float ss = red16(v0[j] + v1[j]);
      const float qq = red16(v0[j] * v0[j] + v1[j] * v1[j]);
      if (lrow == 0) {
        const int r = wm * 16 + lk8 * 4 + j;
        sm.part[r * 4 + wn] = make_float4(ss, qq, 0.f, 0.f);
      }
    }
    __syncthreads();
    // LN-apply + h write (h ALIASES lf cols 0..127 — all lf MFMA reads done at the barrier)
    {
      const float g0 = sm.hg[bn0], g1 = sm.hg[bn1];
      const float e0 = sm.hbe[bn0], e1 = sm.hbe[bn1];
      #pragma unroll
      for (int j = 0; j < 4; ++j) {
        const int r = wm * 16 + lk8 * 4 + j;
        const float4 pA = sm.part[r * 4 + 0], pB = sm.part[r * 4 + 1];
        const float4 pC = sm.part[r * 4 + 2], pD = sm.part[r * 4 + 3];
        const float mean = (pA.x + pB.x + pC.x + pD.x) * (1.f / 128.f);
        const float var  = (pA.y + pB.y + pC.y + pD.y) * (1.f / 128.f) - mean * mean;
        const float rs = rsqrtf(var + 1e-5f);
        float y0 = (v0[j] - mean) * rs * g0 + e0; y0 = (y0 > 0.f) ? y0 : 0.2f * y0;
        float y1 = (v1[j] - mean) * rs * g1 + e1; y1 = (y1 > 0.f) ? y1 : 0.2f * y1;
        sm.lf[r][bn0] = (__bf16)y0;   // h-tile aliased into lf
        sm.lf[r][bn1] = (__bf16)y1;
      }
    }
    __syncthreads();

    // ========== G2: h2 = h @ W2^T (64x128x128), leaky + fused h3 dot ==========
    f32x4 d0 = {0.f, 0.f, 0.f, 0.f}, d1 = d0;
    #pragma unroll
    for (int kk = 0; kk < 4; ++kk) {
      const int ko = kk * 32 + lk8 * 8;
      const bf16x8 fa  = *(const bf16x8*)&sm.lf[am0][ko];   // h-tile
      const bf16x8 fb0 = *(const bf16x8*)&sm.w2f[(((wn * 4 + kk) * 2 + 0) * 64 + lane) * 8];
      const bf16x8 fb1 = *(const bf16x8*)&sm.w2f[(((wn * 4 + kk) * 2 + 1) * 64 + lane) * 8];
      d0 = __builtin_amdgcn_mfma_f32_16x16x32_bf16(fa, fb0, d0, 0, 0, 0);
      d1 = __builtin_amdgcn_mfma_f32_16x16x32_bf16(fa, fb1, d1, 0, 0, 0);
    }
    {
      const float b20 = sm.h2b[bn0], b21 = sm.h2b[bn1];
      const float4 wa = sm.w3t[bn0], wb = sm.w3t[bn1];
      #pragma unroll
      for (int j = 0; j < 4; ++j) {
        float x0 = d0[j] + b20; x0 = (x0 > 0.f) ? x0 : 0.2f * x0;
        float x1 = d1[j] + b21; x1 = (x1 > 0.f) ? x1 : 0.2f * x1;
        const float p0 = red16(x0 * wa.x + x1 * wb.x);
        const float p1 = red16(x0 * wa.y + x1 * wb.y);
        const float p2 = red16(x0 * wa.z + x1 * wb.z);
        if (lrow == 0) {
          const int r = wm * 16 + lk8 * 4 + j;
          sm.part[r * 4 + wn] = make_float4(p0, p1, p2, 0.f);
        }
      }
    }
    __syncthreads();

    // ========== G3: out = unit(cur + delta) ==========
    if (tid < 64) {
      const int r = tid;
      const float4 qa = sm.part[r * 4 + 0], qb = sm.part[r * 4 + 1];
      const float4 qc = sm.part[r * 4 + 2], qd = sm.part[r * 4 + 3];
      const float ox = sm.scal[r][0] + qa.x + qb.x + qc.x + qd.x + sm.h3b[0];
      const float oy = sm.scal[r][1] + qa.y + qb.y + qc.y + qd.y + sm.h3b[1];
      const float oz = sm.scal[r][2] + qa.z + qb.z + qc.z + qd.z + sm.h3b[2];
      const float nn = sqrtf(ox * ox + oy * oy + oz * oz);
      const float iv = 1.f / fmaxf(nn, 1e-6f);
      const size_t o0 = (size_t)(rg0 + r) * 3;
      out[o0 + 0] = ox * iv; out[o0 + 1] = oy * iv; out[o0 + 2] = oz * iv;
    }
    __syncthreads();  // protect lf/scal/part before next tile
  }
}

extern "C" void kernel_launch(void* const* d_in, const int* in_sizes, int n_in,
                              void* d_out, int out_size, void* d_ws, size_t ws_size,
                              hipStream_t stream) {
  (void)in_sizes; (void)n_in; (void)out_size; (void)ws_size;
  const float* jf   = (const float*)d_in[0];
  // d_in[1] = pose_2d (unused by the reference)
  const float* p3   = (const float*)d_in[2];
  const float* az   = (const float*)d_in[3];
  const float* el   = (const float*)d_in[4];
  const float* p2d  = (const float*)d_in[5];
  const float* cow  = (const float*)d_in[6];
  const float* cob  = (const float*)d_in[7];
  const float* cog  = (const float*)d_in[8];
  const float* cobe = (const float*)d_in[9];
  const float* l2w  = (const float*)d_in[10];
  const float* l2b  = (const float*)d_in[11];
  const float* l2g  = (const float*)d_in[12];
  const float* l2be = (const float*)d_in[13];
  const float* vw   = (const float*)d_in[14];
  const float* vb   = (const float*)d_in[15];
  const float* w1   = (const float*)d_in[16];
  const float* h1b  = (const float*)d_in[17];
  const float* hg   = (const float*)d_in[18];
  const float* hbe  = (const float*)d_in[19];
  const float* w2   = (const float*)d_in[20];
  const float* h2b  = (const float*)d_in[21];
  const float* w3   = (const float*)d_in[22];
  const float* h3b  = (const float*)d_in[23];

  __bf16* wsb = (__bf16*)d_ws;

  prep_kernel<<<dim3(24), dim3(256), 0, stream>>>(w1, w2, wsb);
  limb_kernel<<<dim3(NBLK), dim3(NTHR), 0, stream>>>(
      jf, p3, az, el, p2d, cow, cob, cog, cobe,
      l2w, l2b, l2g, l2be, vw, vb,
      h1b, hg, hbe, h2b, w3, h3b, wsb, (float*)d_out);
}